// Round 19
// baseline (140.597 us; speedup 1.0000x reference)
//
#include <hip/hip_runtime.h>
#include <hip/hip_bf16.h>
#include <hip/hip_fp16.h>

// GraphSAGE fwd, round 19.
// Structure = R17 (best reproducible 129us) with ONE change: BSZ 128->64
// (NBP 2048, CAP 2048). R18 counters showed baggr32s ran at 3.05 blocks/CU
// (782-block grid vs 4-block/CU cap) -> 47% occupancy on a latency-bound
// gather. 1563 blocks + 14KB LDS fills all 4 slots.
// lin0 folded into conv1; conv2 collapsed to per-node scalars; fused
// bucket build; cache-phased conv1 gather; light MFMA conv1fused kernel.

#define IN_X 32
#define IN_E 64
#define HID 128
#define OUTF 64

#define BSHIFT 6
#define BSZ 64           // nodes per bucket
#define NBP 2048         // padded bucket count
#define CHUNK 4096       // edges per scatter block
#define CAP 2048         // slots per bucket (mean 1280, +21 sigma)

typedef _Float16 f16x8 __attribute__((ext_vector_type(8)));
typedef float f32x4 __attribute__((ext_vector_type(4)));

__device__ __forceinline__ float2 h2f2(uint v) {
  __half2 h = *reinterpret_cast<__half2*>(&v);
  return __half22float2(h);
}
__device__ __forceinline__ __half2 u2h(uint v) {
  return *reinterpret_cast<__half2*>(&v);
}
__device__ __forceinline__ uint h2u(__half2 h) {
  return *reinterpret_cast<uint*>(&h);
}

// ---------- prep: U1T/U2T, c1, head consts, svecs, zero gcursor, xh ----------
__global__ __launch_bounds__(256) void k_prep(
    const float* __restrict__ W0, const float* __restrict__ b0,
    const float* __restrict__ W1l, const float* __restrict__ b1l,
    const float* __restrict__ W1r,
    const float* __restrict__ W2l, const float* __restrict__ W2r,
    const float* __restrict__ b2l, const float* __restrict__ Wp,
    __half* __restrict__ U1T, __half* __restrict__ U2T, float* __restrict__ c1,
    float* __restrict__ svecs, float* __restrict__ hb, int* __restrict__ gcursor,
    const float* __restrict__ x, __half* __restrict__ xh, int xtotal) {
  const int blk = blockIdx.x;
  if (blk < 32) {
    __shared__ float sW0[IN_X * IN_E];
    for (int t = threadIdx.x; t < IN_X * IN_E; t += 256) sW0[t] = W0[t];
    __syncthreads();
    const int o = blk * 256 + threadIdx.x;
    const int hf = o >> 12;
    const int rem = o & 4095;
    const int j = rem >> 5, i = rem & 31;
    const float* W = hf ? W1r : W1l;
    float u = 0.f;
    #pragma unroll 8
    for (int k = 0; k < IN_E; ++k) u += sW0[i * IN_E + k] * W[k * HID + j];
    (hf ? U2T : U1T)[j * IN_X + i] = __float2half(u);
  } else if (blk == 32) {
    const int j = threadIdx.x;
    if (j < HID) {
      float cv = b1l[j];
      for (int k = 0; k < IN_E; ++k)
        cv += b0[k] * (W1l[k * HID + j] + W1r[k * HID + j]);
      c1[j] = cv;
    } else if (j == HID || j == HID + 1) {
      const float* w = Wp + (j - HID) * OUTF;
      float s = 0.f;
      for (int k = 0; k < OUTF; ++k) s += b2l[k] * w[k];
      hb[j - HID] = s;
    }
  } else if (blk == 33 || blk == 34) {
    __shared__ float sW[HID * OUTF];   // 32 KB
    const float* W = (blk == 33) ? W2l : W2r;
    for (int t = threadIdx.x; t < HID * OUTF; t += 256) sW[t] = W[t];
    __syncthreads();
    const int vec = threadIdx.x >> 7;
    const int j = threadIdx.x & 127;
    const float* w = Wp + vec * OUTF;
    float s = 0.f;
    #pragma unroll 8
    for (int k = 0; k < OUTF; ++k) s += sW[j * OUTF + k] * w[k];
    svecs[(blk - 33) * 256 + vec * 128 + j] = s;
  } else if (blk == 35) {
    #pragma unroll
    for (int k = 0; k < NBP / 256; ++k) gcursor[k * 256 + threadIdx.x] = 0;
  } else {
    int i = ((blk - 36) * 256 + threadIdx.x) * 8;
    if (i < xtotal) {
      float4 a = *(const float4*)(x + i);
      float4 b = *(const float4*)(x + i + 4);
      __half2 h0 = __floats2half2_rn(a.x, a.y);
      __half2 h1 = __floats2half2_rn(a.z, a.w);
      __half2 h2 = __floats2half2_rn(b.x, b.y);
      __half2 h3 = __floats2half2_rn(b.z, b.w);
      uint4 o = { *(uint*)&h0, *(uint*)&h1, *(uint*)&h2, *(uint*)&h3 };
      *(uint4*)(xh + i) = o;
    }
  }
}

// ---------- fused bucket build: hist -> global reserve -> scatter ----------
__global__ __launch_bounds__(512) void k_scatfuse(const int* __restrict__ src,
    const int* __restrict__ dst, int* __restrict__ gcursor,
    uint* __restrict__ bucketData, int E) {
  __shared__ int hist[NBP];   // 8 KB
  const int cblk = blockIdx.x;
  for (int i = threadIdx.x; i < NBP; i += 512) hist[i] = 0;
  __syncthreads();
  const int base = cblk * CHUNK;
  int d[CHUNK / 512], s[CHUNK / 512];
  #pragma unroll
  for (int k = 0; k < CHUNK / 512; ++k) {
    int e = base + k * 512 + threadIdx.x;
    d[k] = (e < E) ? dst[e] : -1;
    s[k] = (e < E) ? src[e] : 0;
  }
  #pragma unroll
  for (int k = 0; k < CHUNK / 512; ++k)
    if (d[k] >= 0) atomicAdd(&hist[d[k] >> BSHIFT], 1);
  __syncthreads();
  for (int i = threadIdx.x; i < NBP; i += 512) {
    int h = hist[i];
    hist[i] = (h > 0) ? atomicAdd(&gcursor[i], h) : 0;
  }
  __syncthreads();
  #pragma unroll
  for (int k = 0; k < CHUNK / 512; ++k) {
    if (d[k] >= 0) {
      int bkt = d[k] >> BSHIFT;
      int pos = atomicAdd(&hist[bkt], 1);
      if (pos < CAP)
        bucketData[(size_t)bkt * CAP + pos] =
            ((uint)s[k] << BSHIFT) | (uint)(d[k] & (BSZ - 1));
    }
  }
}

// ---------- conv1 aggregation (cache-phased, 4-node interleave) ----------
__global__ __launch_bounds__(512) void k_baggr32s(const __half* __restrict__ feat,
    const uint* __restrict__ bucketData, const int* __restrict__ gcnt,
    __half* __restrict__ aggr, uint* __restrict__ gorder,
    int* __restrict__ gns, int* __restrict__ gne, int N, int Nhalf) {
  constexpr int FW = IN_X;     // 32 halves per row
  __shared__ int nodeStart[2 * BSZ + 1];   // 129 ints
  __shared__ int cursor[2 * BSZ];          // 128 ints
  __shared__ int order[CAP];               // 8 KB
  __shared__ uint2 stash[BSZ * 8];         // 4 KB packed-fp16 partials
  const int b = blockIdx.x;
  const int tid = threadIdx.x;
  const int lane = tid & 63, wid = tid >> 6;
  const int e0 = b * CAP;
  const int cnt = min(gcnt[b], CAP);

  for (int i = tid; i < 2 * BSZ; i += 512) cursor[i] = 0;
  __syncthreads();
  for (int i = tid; i < cnt; i += 512) {
    uint p = bucketData[e0 + i];
    int key = ((p & (BSZ - 1)) << 1) | ((int)(p >> BSHIFT) >= Nhalf ? 1 : 0);
    atomicAdd(&cursor[key], 1);
  }
  __syncthreads();

  // exclusive scan over 128 counters (wave 0, 2 segments of 64 with carry)
  if (wid == 0) {
    int carry = 0;
    #pragma unroll
    for (int seg = 0; seg < 2; ++seg) {
      int v = cursor[seg * 64 + lane];
      int x = v;
      #pragma unroll
      for (int s = 1; s < 64; s <<= 1) {
        int y = __shfl_up(x, s, 64);
        if (lane >= s) x += y;
      }
      nodeStart[seg * 64 + lane] = carry + x - v;
      carry += __shfl(x, 63, 64);
    }
    if (lane == 0) nodeStart[2 * BSZ] = carry;
  }
  __syncthreads();
  for (int i = tid; i < 2 * BSZ; i += 512) cursor[i] = nodeStart[i];
  __syncthreads();

  for (int i = tid; i < cnt; i += 512) {
    uint p = bucketData[e0 + i];
    int key = ((p & (BSZ - 1)) << 1) | ((int)(p >> BSHIFT) >= Nhalf ? 1 : 0);
    int pos = atomicAdd(&cursor[key], 1);
    order[pos] = (int)(p >> BSHIFT);
  }
  __syncthreads();

  // export gapped CSR
  for (int i = tid; i < cnt; i += 512) gorder[e0 + i] = (uint)order[i];
  if (tid < BSZ) {
    const int n = b * BSZ + tid;
    if (n < N) {
      gns[n] = e0 + nodeStart[2 * tid];
      gne[n] = e0 + nodeStart[2 * tid + 2];
    }
  }

  const int nodes = min(BSZ, N - b * BSZ);
  const int g = lane >> 3, e = lane & 7;   // 8 lanes x uint2 = 64B row

  // two phases (ph=0: low-half srcs, ph=1: high-half), 4 nodes interleaved
  #pragma unroll
  for (int ph = 0; ph < 2; ++ph) {
    for (int k = 0; k < BSZ / 8; k += 4) {
      const int n0 = wid + 8 * k,        n1 = wid + 8 * (k + 1);
      const int n2 = wid + 8 * (k + 2),  n3 = wid + 8 * (k + 3);
      int j0 = (n0 < nodes) ? nodeStart[2 * n0 + ph] : 0;
      int t0 = (n0 < nodes) ? nodeStart[2 * n0 + ph + 1] : 0;
      int j1 = (n1 < nodes) ? nodeStart[2 * n1 + ph] : 0;
      int t1 = (n1 < nodes) ? nodeStart[2 * n1 + ph + 1] : 0;
      int j2 = (n2 < nodes) ? nodeStart[2 * n2 + ph] : 0;
      int t2 = (n2 < nodes) ? nodeStart[2 * n2 + ph + 1] : 0;
      int j3 = (n3 < nodes) ? nodeStart[2 * n3 + ph] : 0;
      int t3 = (n3 < nodes) ? nodeStart[2 * n3 + ph + 1] : 0;
      __half2 ax0 = __floats2half2_rn(0.f, 0.f), ay0 = ax0;
      __half2 ax1 = ax0, ay1 = ax0, ax2 = ax0, ay2 = ax0, ax3 = ax0, ay3 = ax0;
      while (j0 < t0 || j1 < t1 || j2 < t2 || j3 < t3) {
        uint2 v0, v1, v2, v3;
        const bool a0 = j0 + g < t0, a1 = j1 + g < t1;
        const bool a2 = j2 + g < t2, a3 = j3 + g < t3;
        if (a0) { int r = order[j0 + g]; v0 = ((const uint2*)(feat + (size_t)r * FW))[e]; }
        if (a1) { int r = order[j1 + g]; v1 = ((const uint2*)(feat + (size_t)r * FW))[e]; }
        if (a2) { int r = order[j2 + g]; v2 = ((const uint2*)(feat + (size_t)r * FW))[e]; }
        if (a3) { int r = order[j3 + g]; v3 = ((const uint2*)(feat + (size_t)r * FW))[e]; }
        if (a0) { ax0 = __hadd2(ax0, u2h(v0.x)); ay0 = __hadd2(ay0, u2h(v0.y)); }
        if (a1) { ax1 = __hadd2(ax1, u2h(v1.x)); ay1 = __hadd2(ay1, u2h(v1.y)); }
        if (a2) { ax2 = __hadd2(ax2, u2h(v2.x)); ay2 = __hadd2(ay2, u2h(v2.y)); }
        if (a3) { ax3 = __hadd2(ax3, u2h(v3.x)); ay3 = __hadd2(ay3, u2h(v3.y)); }
        j0 += 8; j1 += 8; j2 += 8; j3 += 8;
      }
      // reduce across the 8 row-groups (m = 8,16,32)
      #pragma unroll
      for (int m = 8; m < 64; m <<= 1) {
        ax0 = __hadd2(ax0, u2h((uint)__shfl_xor((int)h2u(ax0), m, 64)));
        ay0 = __hadd2(ay0, u2h((uint)__shfl_xor((int)h2u(ay0), m, 64)));
        ax1 = __hadd2(ax1, u2h((uint)__shfl_xor((int)h2u(ax1), m, 64)));
        ay1 = __hadd2(ay1, u2h((uint)__shfl_xor((int)h2u(ay1), m, 64)));
        ax2 = __hadd2(ax2, u2h((uint)__shfl_xor((int)h2u(ax2), m, 64)));
        ay2 = __hadd2(ay2, u2h((uint)__shfl_xor((int)h2u(ay2), m, 64)));
        ax3 = __hadd2(ax3, u2h((uint)__shfl_xor((int)h2u(ax3), m, 64)));
        ay3 = __hadd2(ay3, u2h((uint)__shfl_xor((int)h2u(ay3), m, 64)));
      }
      if (g == 0) {
        if (ph == 0) {
          if (n0 < nodes) stash[n0 * 8 + e] = make_uint2(h2u(ax0), h2u(ay0));
          if (n1 < nodes) stash[n1 * 8 + e] = make_uint2(h2u(ax1), h2u(ay1));
          if (n2 < nodes) stash[n2 * 8 + e] = make_uint2(h2u(ax2), h2u(ay2));
          if (n3 < nodes) stash[n3 * 8 + e] = make_uint2(h2u(ax3), h2u(ay3));
        } else {
          if (n0 < nodes) {
            uint2 st = stash[n0 * 8 + e];
            ax0 = __hadd2(ax0, u2h(st.x)); ay0 = __hadd2(ay0, u2h(st.y));
            const int deg = nodeStart[2 * n0 + 2] - nodeStart[2 * n0];
            float inv = 1.f / fmaxf((float)deg, 1.f);
            float2 fx = __half22float2(ax0), fy = __half22float2(ay0);
            __half2 o0 = __floats2half2_rn(fx.x * inv, fx.y * inv);
            __half2 o1 = __floats2half2_rn(fy.x * inv, fy.y * inv);
            ((uint2*)(aggr + ((size_t)(b * BSZ + n0)) * FW))[e] = make_uint2(h2u(o0), h2u(o1));
          }
          if (n1 < nodes) {
            uint2 st = stash[n1 * 8 + e];
            ax1 = __hadd2(ax1, u2h(st.x)); ay1 = __hadd2(ay1, u2h(st.y));
            const int deg = nodeStart[2 * n1 + 2] - nodeStart[2 * n1];
            float inv = 1.f / fmaxf((float)deg, 1.f);
            float2 fx = __half22float2(ax1), fy = __half22float2(ay1);
            __half2 o0 = __floats2half2_rn(fx.x * inv, fx.y * inv);
            __half2 o1 = __floats2half2_rn(fy.x * inv, fy.y * inv);
            ((uint2*)(aggr + ((size_t)(b * BSZ + n1)) * FW))[e] = make_uint2(h2u(o0), h2u(o1));
          }
          if (n2 < nodes) {
            uint2 st = stash[n2 * 8 + e];
            ax2 = __hadd2(ax2, u2h(st.x)); ay2 = __hadd2(ay2, u2h(st.y));
            const int deg = nodeStart[2 * n2 + 2] - nodeStart[2 * n2];
            float inv = 1.f / fmaxf((float)deg, 1.f);
            float2 fx = __half22float2(ax2), fy = __half22float2(ay2);
            __half2 o0 = __floats2half2_rn(fx.x * inv, fx.y * inv);
            __half2 o1 = __floats2half2_rn(fy.x * inv, fy.y * inv);
            ((uint2*)(aggr + ((size_t)(b * BSZ + n2)) * FW))[e] = make_uint2(h2u(o0), h2u(o1));
          }
          if (n3 < nodes) {
            uint2 st = stash[n3 * 8 + e];
            ax3 = __hadd2(ax3, u2h(st.x)); ay3 = __hadd2(ay3, u2h(st.y));
            const int deg = nodeStart[2 * n3 + 2] - nodeStart[2 * n3];
            float inv = 1.f / fmaxf((float)deg, 1.f);
            float2 fx = __half22float2(ax3), fy = __half22float2(ay3);
            __half2 o0 = __floats2half2_rn(fx.x * inv, fx.y * inv);
            __half2 o1 = __floats2half2_rn(fy.x * inv, fy.y * inv);
            ((uint2*)(aggr + ((size_t)(b * BSZ + n3)) * FW))[e] = make_uint2(h2u(o0), h2u(o1));
          }
        }
      }
    }
    if (ph == 0) __syncthreads();   // switch L2 working set
  }
}

// ---------- fused conv1 lin + scalar head projections ----------
__global__ __launch_bounds__(256) void k_conv1fused(
    const __half* __restrict__ axm, const __half* __restrict__ xh,
    const __half* __restrict__ U1T, const __half* __restrict__ U2T,
    const float* __restrict__ c1, const float* __restrict__ svecs,
    float2* __restrict__ tsd, float2* __restrict__ ssd, int N) {
  __shared__ _Float16 tile[4][16 * HID];
  __shared__ float svec[512];    // [vs|vd|us|ud]
  const int lane = threadIdx.x & 63;
  const int wid = threadIdx.x >> 6;
  const int row0 = blockIdx.x * 64 + wid * 16;
  const int lr = lane & 15;
  const int lk = (lane >> 4) * 8;

  for (int i = threadIdx.x; i < 512; i += 256) svec[i] = svecs[i];

  {
    f16x8 b1[8], b2[8];
    #pragma unroll
    for (int ct = 0; ct < 8; ++ct) {
      const int c = ct * 16 + lr;
      b1[ct] = *(const f16x8*)((const _Float16*)U1T + (size_t)c * IN_X + lk);
      b2[ct] = *(const f16x8*)((const _Float16*)U2T + (size_t)c * IN_X + lk);
    }
    f32x4 acc[8];
    #pragma unroll
    for (int ct = 0; ct < 8; ++ct) {
      float bv = c1[ct * 16 + lr];
      acc[ct] = (f32x4){bv, bv, bv, bv};
    }
    const int rA = min(row0 + lr, N - 1);
    f16x8 a1 = *(const f16x8*)((const _Float16*)axm + (size_t)rA * IN_X + lk);
    f16x8 a2 = *(const f16x8*)((const _Float16*)xh + (size_t)rA * IN_X + lk);
    #pragma unroll
    for (int ct = 0; ct < 8; ++ct)
      acc[ct] = __builtin_amdgcn_mfma_f32_16x16x32_f16(a1, b1[ct], acc[ct], 0, 0, 0);
    #pragma unroll
    for (int ct = 0; ct < 8; ++ct)
      acc[ct] = __builtin_amdgcn_mfma_f32_16x16x32_f16(a2, b2[ct], acc[ct], 0, 0, 0);
    #pragma unroll
    for (int ct = 0; ct < 8; ++ct) {
      #pragma unroll
      for (int r = 0; r < 4; ++r) {
        const int row = (lane >> 4) * 4 + r;
        const int col = ct * 16 + lr;
        int idx = (row * HID + col) ^ ((row & 7) << 3);
        tile[wid][idx] = (_Float16)fmaxf(acc[ct][r], 0.f);
      }
    }
  }
  __syncthreads();

  const int row = lane & 15, q = lane >> 4;
  float ts = 0.f, td = 0.f, ss = 0.f, sd = 0.f;
  #pragma unroll
  for (int t = 0; t < 4; ++t) {
    const int col = q * 32 + t * 8;
    int idx = (row * HID + col) ^ ((row & 7) << 3);
    f16x8 h = *(const f16x8*)&tile[wid][idx];
    #pragma unroll
    for (int i = 0; i < 8; ++i) {
      float hv = (float)h[i];
      ts += hv * svec[col + i];
      td += hv * svec[128 + col + i];
      ss += hv * svec[256 + col + i];
      sd += hv * svec[384 + col + i];
    }
  }
  ts += __shfl_xor(ts, 16, 64); ts += __shfl_xor(ts, 32, 64);
  td += __shfl_xor(td, 16, 64); td += __shfl_xor(td, 32, 64);
  ss += __shfl_xor(ss, 16, 64); ss += __shfl_xor(ss, 32, 64);
  sd += __shfl_xor(sd, 16, 64); sd += __shfl_xor(sd, 32, 64);
  if (q == 0) {
    const int grow = row0 + row;
    if (grow < N) {
      tsd[grow] = make_float2(ts, td);
      ssd[grow] = make_float2(ss, sd);
    }
  }
}

// ---------- conv2 scalar aggregation ----------
__global__ __launch_bounds__(256) void k_scalagg(const float2* __restrict__ tsd,
    const float2* __restrict__ ssd, const int* __restrict__ gns,
    const int* __restrict__ gne, const uint* __restrict__ gorder,
    const float* __restrict__ hb,
    float* __restrict__ gs, float* __restrict__ gd, int N) {
  const int n = blockIdx.x * 256 + threadIdx.x;
  if (n >= N) return;
  const int s = gns[n], t = gne[n];
  float ax = 0.f, ay = 0.f;
  int j = s;
  for (; j + 4 <= t; j += 4) {
    int r0 = (int)gorder[j],     r1 = (int)gorder[j + 1];
    int r2 = (int)gorder[j + 2], r3 = (int)gorder[j + 3];
    float2 a = tsd[r0], b = tsd[r1], c = tsd[r2], d = tsd[r3];
    ax += (a.x + b.x) + (c.x + d.x);
    ay += (a.y + b.y) + (c.y + d.y);
  }
  for (; j < t; ++j) {
    float2 a = tsd[(int)gorder[j]];
    ax += a.x; ay += a.y;
  }
  const float inv = 1.f / fmaxf((float)(t - s), 1.f);
  const float2 sv = ssd[n];
  gs[n] = sv.x + ax * inv + hb[0];
  gd[n] = sv.y + ay * inv + hb[1];
}

// ---------- per-edge: raw = gs[src] + gd[dst] + bp; sigmoid ----------
__global__ __launch_bounds__(256) void k_edge(const float* __restrict__ gs,
    const float* __restrict__ gd, const int* __restrict__ srcI,
    const int* __restrict__ dstI, const float* __restrict__ bp,
    float* __restrict__ out, int E) {
  int e = blockIdx.x * 256 + threadIdx.x;
  if (e >= E) return;
  float raw = gs[srcI[e]] + gd[dstI[e]] + bp[0];
  out[e] = raw;
  out[(size_t)E + e] = 1.f / (1.f + expf(-raw));
}

extern "C" void kernel_launch(void* const* d_in, const int* in_sizes, int n_in,
                              void* d_out, int out_size, void* d_ws, size_t ws_size,
                              hipStream_t stream) {
  const float* x   = (const float*)d_in[0];
  const int*   ei  = (const int*)d_in[1];
  const float* W0  = (const float*)d_in[2];
  const float* b0  = (const float*)d_in[3];
  const float* W1l = (const float*)d_in[4];
  const float* b1l = (const float*)d_in[5];
  const float* W1r = (const float*)d_in[6];
  const float* W2l = (const float*)d_in[7];
  const float* b2l = (const float*)d_in[8];
  const float* W2r = (const float*)d_in[9];
  const float* Wp  = (const float*)d_in[10];
  const float* bp  = (const float*)d_in[11];

  const int N = in_sizes[0] / IN_X;
  const int E = in_sizes[1] / 2;
  const int* srcI = ei;
  const int* dstI = ei + E;
  float* out = (float*)d_out;

  const int NB = (N + BSZ - 1) >> BSHIFT;
  const int nchunk = (E + CHUNK - 1) / CHUNK;

  // workspace layout
  __half* xh  = (__half*)d_ws;                   // [N][32]
  __half* axm = xh + (size_t)N * IN_X;           // [N][32]
  float2* tsd = (float2*)(axm + (size_t)N * IN_X);  // [N]
  float2* ssd = tsd + N;                         // [N]
  float* gs   = (float*)(ssd + N);               // [N]
  float* gd   = gs + N;                          // [N]
  uintptr_t wp = ((uintptr_t)(gd + N) + 15) & ~(uintptr_t)15;
  __half* U1T  = (__half*)wp;                    // [128][32]
  __half* U2T  = U1T + HID * IN_X;
  float* c1    = (float*)(U2T + HID * IN_X);     // [128]
  float* svecs = c1 + HID;                       // [512] = vs|vd|us|ud
  float* hb    = svecs + 512;                    // [2]
  int* gcursor = (int*)(hb + 2);                 // [NBP]
  int* gns     = gcursor + NBP;                  // [N+1]
  int* gne     = gns + N + 1;                    // [N]
  uint* bucketData = (uint*)(gne + N);           // [NBP*CAP]
  uint* gorder     = bucketData + (size_t)NBP * CAP;  // [NBP*CAP]

  const int xblocks = (N * IN_X / 8 + 255) / 256;
  k_prep<<<36 + xblocks, 256, 0, stream>>>(W0, b0, W1l, b1l, W1r, W2l, W2r,
                                           b2l, Wp, U1T, U2T, c1, svecs, hb,
                                           gcursor, x, xh, N * IN_X);
  // fused bucket build
  k_scatfuse<<<nchunk, 512, 0, stream>>>(srcI, dstI, gcursor, bucketData, E);
  // conv1: axm = mean(xh_j) cache-phased + 4-node interleave
  k_baggr32s<<<NB, 512, 0, stream>>>(xh, bucketData, gcursor, axm, gorder,
                                     gns, gne, N, N / 2);
  // fused conv1 lin + scalar head projections
  k_conv1fused<<<(N + 63) / 64, 256, 0, stream>>>(axm, xh, U1T, U2T, c1,
                                                  svecs, tsd, ssd, N);
  // conv2 scalar aggregation
  k_scalagg<<<(N + 255) / 256, 256, 0, stream>>>(tsd, ssd, gns, gne, gorder,
                                                 hb, gs, gd, N);
  // edge head
  k_edge<<<(E + 255) / 256, 256, 0, stream>>>(gs, gd, srcI, dstI, bp, out, E);
}

// Round 20
// 140.327 us; speedup vs baseline: 1.0019x; 1.0019x over previous
//
#include <hip/hip_runtime.h>
#include <hip/hip_bf16.h>
#include <hip/hip_fp16.h>

// GraphSAGE fwd, round 19.
// Structure = R17 (best reproducible 129us) with ONE change: BSZ 128->64
// (NBP 2048, CAP 2048). R18 counters showed baggr32s ran at 3.05 blocks/CU
// (782-block grid vs 4-block/CU cap) -> 47% occupancy on a latency-bound
// gather. 1563 blocks + 14KB LDS fills all 4 slots.
// lin0 folded into conv1; conv2 collapsed to per-node scalars; fused
// bucket build; cache-phased conv1 gather; light MFMA conv1fused kernel.

#define IN_X 32
#define IN_E 64
#define HID 128
#define OUTF 64

#define BSHIFT 6
#define BSZ 64           // nodes per bucket
#define NBP 2048         // padded bucket count
#define CHUNK 4096       // edges per scatter block
#define CAP 2048         // slots per bucket (mean 1280, +21 sigma)

typedef _Float16 f16x8 __attribute__((ext_vector_type(8)));
typedef float f32x4 __attribute__((ext_vector_type(4)));

__device__ __forceinline__ float2 h2f2(uint v) {
  __half2 h = *reinterpret_cast<__half2*>(&v);
  return __half22float2(h);
}
__device__ __forceinline__ __half2 u2h(uint v) {
  return *reinterpret_cast<__half2*>(&v);
}
__device__ __forceinline__ uint h2u(__half2 h) {
  return *reinterpret_cast<uint*>(&h);
}

// ---------- prep: U1T/U2T, c1, head consts, svecs, zero gcursor, xh ----------
__global__ __launch_bounds__(256) void k_prep(
    const float* __restrict__ W0, const float* __restrict__ b0,
    const float* __restrict__ W1l, const float* __restrict__ b1l,
    const float* __restrict__ W1r,
    const float* __restrict__ W2l, const float* __restrict__ W2r,
    const float* __restrict__ b2l, const float* __restrict__ Wp,
    __half* __restrict__ U1T, __half* __restrict__ U2T, float* __restrict__ c1,
    float* __restrict__ svecs, float* __restrict__ hb, int* __restrict__ gcursor,
    const float* __restrict__ x, __half* __restrict__ xh, int xtotal) {
  const int blk = blockIdx.x;
  if (blk < 32) {
    __shared__ float sW0[IN_X * IN_E];
    for (int t = threadIdx.x; t < IN_X * IN_E; t += 256) sW0[t] = W0[t];
    __syncthreads();
    const int o = blk * 256 + threadIdx.x;
    const int hf = o >> 12;
    const int rem = o & 4095;
    const int j = rem >> 5, i = rem & 31;
    const float* W = hf ? W1r : W1l;
    float u = 0.f;
    #pragma unroll 8
    for (int k = 0; k < IN_E; ++k) u += sW0[i * IN_E + k] * W[k * HID + j];
    (hf ? U2T : U1T)[j * IN_X + i] = __float2half(u);
  } else if (blk == 32) {
    const int j = threadIdx.x;
    if (j < HID) {
      float cv = b1l[j];
      for (int k = 0; k < IN_E; ++k)
        cv += b0[k] * (W1l[k * HID + j] + W1r[k * HID + j]);
      c1[j] = cv;
    } else if (j == HID || j == HID + 1) {
      const float* w = Wp + (j - HID) * OUTF;
      float s = 0.f;
      for (int k = 0; k < OUTF; ++k) s += b2l[k] * w[k];
      hb[j - HID] = s;
    }
  } else if (blk == 33 || blk == 34) {
    __shared__ float sW[HID * OUTF];   // 32 KB
    const float* W = (blk == 33) ? W2l : W2r;
    for (int t = threadIdx.x; t < HID * OUTF; t += 256) sW[t] = W[t];
    __syncthreads();
    const int vec = threadIdx.x >> 7;
    const int j = threadIdx.x & 127;
    const float* w = Wp + vec * OUTF;
    float s = 0.f;
    #pragma unroll 8
    for (int k = 0; k < OUTF; ++k) s += sW[j * OUTF + k] * w[k];
    svecs[(blk - 33) * 256 + vec * 128 + j] = s;
  } else if (blk == 35) {
    #pragma unroll
    for (int k = 0; k < NBP / 256; ++k) gcursor[k * 256 + threadIdx.x] = 0;
  } else {
    int i = ((blk - 36) * 256 + threadIdx.x) * 8;
    if (i < xtotal) {
      float4 a = *(const float4*)(x + i);
      float4 b = *(const float4*)(x + i + 4);
      __half2 h0 = __floats2half2_rn(a.x, a.y);
      __half2 h1 = __floats2half2_rn(a.z, a.w);
      __half2 h2 = __floats2half2_rn(b.x, b.y);
      __half2 h3 = __floats2half2_rn(b.z, b.w);
      uint4 o = { *(uint*)&h0, *(uint*)&h1, *(uint*)&h2, *(uint*)&h3 };
      *(uint4*)(xh + i) = o;
    }
  }
}

// ---------- fused bucket build: hist -> global reserve -> scatter ----------
__global__ __launch_bounds__(512) void k_scatfuse(const int* __restrict__ src,
    const int* __restrict__ dst, int* __restrict__ gcursor,
    uint* __restrict__ bucketData, int E) {
  __shared__ int hist[NBP];   // 8 KB
  const int cblk = blockIdx.x;
  for (int i = threadIdx.x; i < NBP; i += 512) hist[i] = 0;
  __syncthreads();
  const int base = cblk * CHUNK;
  int d[CHUNK / 512], s[CHUNK / 512];
  #pragma unroll
  for (int k = 0; k < CHUNK / 512; ++k) {
    int e = base + k * 512 + threadIdx.x;
    d[k] = (e < E) ? dst[e] : -1;
    s[k] = (e < E) ? src[e] : 0;
  }
  #pragma unroll
  for (int k = 0; k < CHUNK / 512; ++k)
    if (d[k] >= 0) atomicAdd(&hist[d[k] >> BSHIFT], 1);
  __syncthreads();
  for (int i = threadIdx.x; i < NBP; i += 512) {
    int h = hist[i];
    hist[i] = (h > 0) ? atomicAdd(&gcursor[i], h) : 0;
  }
  __syncthreads();
  #pragma unroll
  for (int k = 0; k < CHUNK / 512; ++k) {
    if (d[k] >= 0) {
      int bkt = d[k] >> BSHIFT;
      int pos = atomicAdd(&hist[bkt], 1);
      if (pos < CAP)
        bucketData[(size_t)bkt * CAP + pos] =
            ((uint)s[k] << BSHIFT) | (uint)(d[k] & (BSZ - 1));
    }
  }
}

// ---------- conv1 aggregation (cache-phased, 4-node interleave) ----------
__global__ __launch_bounds__(512) void k_baggr32s(const __half* __restrict__ feat,
    const uint* __restrict__ bucketData, const int* __restrict__ gcnt,
    __half* __restrict__ aggr, uint* __restrict__ gorder,
    int* __restrict__ gns, int* __restrict__ gne, int N, int Nhalf) {
  constexpr int FW = IN_X;     // 32 halves per row
  __shared__ int nodeStart[2 * BSZ + 1];   // 129 ints
  __shared__ int cursor[2 * BSZ];          // 128 ints
  __shared__ int order[CAP];               // 8 KB
  __shared__ uint2 stash[BSZ * 8];         // 4 KB packed-fp16 partials
  const int b = blockIdx.x;
  const int tid = threadIdx.x;
  const int lane = tid & 63, wid = tid >> 6;
  const int e0 = b * CAP;
  const int cnt = min(gcnt[b], CAP);

  for (int i = tid; i < 2 * BSZ; i += 512) cursor[i] = 0;
  __syncthreads();
  for (int i = tid; i < cnt; i += 512) {
    uint p = bucketData[e0 + i];
    int key = ((p & (BSZ - 1)) << 1) | ((int)(p >> BSHIFT) >= Nhalf ? 1 : 0);
    atomicAdd(&cursor[key], 1);
  }
  __syncthreads();

  // exclusive scan over 128 counters (wave 0, 2 segments of 64 with carry)
  if (wid == 0) {
    int carry = 0;
    #pragma unroll
    for (int seg = 0; seg < 2; ++seg) {
      int v = cursor[seg * 64 + lane];
      int x = v;
      #pragma unroll
      for (int s = 1; s < 64; s <<= 1) {
        int y = __shfl_up(x, s, 64);
        if (lane >= s) x += y;
      }
      nodeStart[seg * 64 + lane] = carry + x - v;
      carry += __shfl(x, 63, 64);
    }
    if (lane == 0) nodeStart[2 * BSZ] = carry;
  }
  __syncthreads();
  for (int i = tid; i < 2 * BSZ; i += 512) cursor[i] = nodeStart[i];
  __syncthreads();

  for (int i = tid; i < cnt; i += 512) {
    uint p = bucketData[e0 + i];
    int key = ((p & (BSZ - 1)) << 1) | ((int)(p >> BSHIFT) >= Nhalf ? 1 : 0);
    int pos = atomicAdd(&cursor[key], 1);
    order[pos] = (int)(p >> BSHIFT);
  }
  __syncthreads();

  // export gapped CSR
  for (int i = tid; i < cnt; i += 512) gorder[e0 + i] = (uint)order[i];
  if (tid < BSZ) {
    const int n = b * BSZ + tid;
    if (n < N) {
      gns[n] = e0 + nodeStart[2 * tid];
      gne[n] = e0 + nodeStart[2 * tid + 2];
    }
  }

  const int nodes = min(BSZ, N - b * BSZ);
  const int g = lane >> 3, e = lane & 7;   // 8 lanes x uint2 = 64B row

  // two phases (ph=0: low-half srcs, ph=1: high-half), 4 nodes interleaved
  #pragma unroll
  for (int ph = 0; ph < 2; ++ph) {
    for (int k = 0; k < BSZ / 8; k += 4) {
      const int n0 = wid + 8 * k,        n1 = wid + 8 * (k + 1);
      const int n2 = wid + 8 * (k + 2),  n3 = wid + 8 * (k + 3);
      int j0 = (n0 < nodes) ? nodeStart[2 * n0 + ph] : 0;
      int t0 = (n0 < nodes) ? nodeStart[2 * n0 + ph + 1] : 0;
      int j1 = (n1 < nodes) ? nodeStart[2 * n1 + ph] : 0;
      int t1 = (n1 < nodes) ? nodeStart[2 * n1 + ph + 1] : 0;
      int j2 = (n2 < nodes) ? nodeStart[2 * n2 + ph] : 0;
      int t2 = (n2 < nodes) ? nodeStart[2 * n2 + ph + 1] : 0;
      int j3 = (n3 < nodes) ? nodeStart[2 * n3 + ph] : 0;
      int t3 = (n3 < nodes) ? nodeStart[2 * n3 + ph + 1] : 0;
      __half2 ax0 = __floats2half2_rn(0.f, 0.f), ay0 = ax0;
      __half2 ax1 = ax0, ay1 = ax0, ax2 = ax0, ay2 = ax0, ax3 = ax0, ay3 = ax0;
      while (j0 < t0 || j1 < t1 || j2 < t2 || j3 < t3) {
        uint2 v0, v1, v2, v3;
        const bool a0 = j0 + g < t0, a1 = j1 + g < t1;
        const bool a2 = j2 + g < t2, a3 = j3 + g < t3;
        if (a0) { int r = order[j0 + g]; v0 = ((const uint2*)(feat + (size_t)r * FW))[e]; }
        if (a1) { int r = order[j1 + g]; v1 = ((const uint2*)(feat + (size_t)r * FW))[e]; }
        if (a2) { int r = order[j2 + g]; v2 = ((const uint2*)(feat + (size_t)r * FW))[e]; }
        if (a3) { int r = order[j3 + g]; v3 = ((const uint2*)(feat + (size_t)r * FW))[e]; }
        if (a0) { ax0 = __hadd2(ax0, u2h(v0.x)); ay0 = __hadd2(ay0, u2h(v0.y)); }
        if (a1) { ax1 = __hadd2(ax1, u2h(v1.x)); ay1 = __hadd2(ay1, u2h(v1.y)); }
        if (a2) { ax2 = __hadd2(ax2, u2h(v2.x)); ay2 = __hadd2(ay2, u2h(v2.y)); }
        if (a3) { ax3 = __hadd2(ax3, u2h(v3.x)); ay3 = __hadd2(ay3, u2h(v3.y)); }
        j0 += 8; j1 += 8; j2 += 8; j3 += 8;
      }
      // reduce across the 8 row-groups (m = 8,16,32)
      #pragma unroll
      for (int m = 8; m < 64; m <<= 1) {
        ax0 = __hadd2(ax0, u2h((uint)__shfl_xor((int)h2u(ax0), m, 64)));
        ay0 = __hadd2(ay0, u2h((uint)__shfl_xor((int)h2u(ay0), m, 64)));
        ax1 = __hadd2(ax1, u2h((uint)__shfl_xor((int)h2u(ax1), m, 64)));
        ay1 = __hadd2(ay1, u2h((uint)__shfl_xor((int)h2u(ay1), m, 64)));
        ax2 = __hadd2(ax2, u2h((uint)__shfl_xor((int)h2u(ax2), m, 64)));
        ay2 = __hadd2(ay2, u2h((uint)__shfl_xor((int)h2u(ay2), m, 64)));
        ax3 = __hadd2(ax3, u2h((uint)__shfl_xor((int)h2u(ax3), m, 64)));
        ay3 = __hadd2(ay3, u2h((uint)__shfl_xor((int)h2u(ay3), m, 64)));
      }
      if (g == 0) {
        if (ph == 0) {
          if (n0 < nodes) stash[n0 * 8 + e] = make_uint2(h2u(ax0), h2u(ay0));
          if (n1 < nodes) stash[n1 * 8 + e] = make_uint2(h2u(ax1), h2u(ay1));
          if (n2 < nodes) stash[n2 * 8 + e] = make_uint2(h2u(ax2), h2u(ay2));
          if (n3 < nodes) stash[n3 * 8 + e] = make_uint2(h2u(ax3), h2u(ay3));
        } else {
          if (n0 < nodes) {
            uint2 st = stash[n0 * 8 + e];
            ax0 = __hadd2(ax0, u2h(st.x)); ay0 = __hadd2(ay0, u2h(st.y));
            const int deg = nodeStart[2 * n0 + 2] - nodeStart[2 * n0];
            float inv = 1.f / fmaxf((float)deg, 1.f);
            float2 fx = __half22float2(ax0), fy = __half22float2(ay0);
            __half2 o0 = __floats2half2_rn(fx.x * inv, fx.y * inv);
            __half2 o1 = __floats2half2_rn(fy.x * inv, fy.y * inv);
            ((uint2*)(aggr + ((size_t)(b * BSZ + n0)) * FW))[e] = make_uint2(h2u(o0), h2u(o1));
          }
          if (n1 < nodes) {
            uint2 st = stash[n1 * 8 + e];
            ax1 = __hadd2(ax1, u2h(st.x)); ay1 = __hadd2(ay1, u2h(st.y));
            const int deg = nodeStart[2 * n1 + 2] - nodeStart[2 * n1];
            float inv = 1.f / fmaxf((float)deg, 1.f);
            float2 fx = __half22float2(ax1), fy = __half22float2(ay1);
            __half2 o0 = __floats2half2_rn(fx.x * inv, fx.y * inv);
            __half2 o1 = __floats2half2_rn(fy.x * inv, fy.y * inv);
            ((uint2*)(aggr + ((size_t)(b * BSZ + n1)) * FW))[e] = make_uint2(h2u(o0), h2u(o1));
          }
          if (n2 < nodes) {
            uint2 st = stash[n2 * 8 + e];
            ax2 = __hadd2(ax2, u2h(st.x)); ay2 = __hadd2(ay2, u2h(st.y));
            const int deg = nodeStart[2 * n2 + 2] - nodeStart[2 * n2];
            float inv = 1.f / fmaxf((float)deg, 1.f);
            float2 fx = __half22float2(ax2), fy = __half22float2(ay2);
            __half2 o0 = __floats2half2_rn(fx.x * inv, fx.y * inv);
            __half2 o1 = __floats2half2_rn(fy.x * inv, fy.y * inv);
            ((uint2*)(aggr + ((size_t)(b * BSZ + n2)) * FW))[e] = make_uint2(h2u(o0), h2u(o1));
          }
          if (n3 < nodes) {
            uint2 st = stash[n3 * 8 + e];
            ax3 = __hadd2(ax3, u2h(st.x)); ay3 = __hadd2(ay3, u2h(st.y));
            const int deg = nodeStart[2 * n3 + 2] - nodeStart[2 * n3];
            float inv = 1.f / fmaxf((float)deg, 1.f);
            float2 fx = __half22float2(ax3), fy = __half22float2(ay3);
            __half2 o0 = __floats2half2_rn(fx.x * inv, fx.y * inv);
            __half2 o1 = __floats2half2_rn(fy.x * inv, fy.y * inv);
            ((uint2*)(aggr + ((size_t)(b * BSZ + n3)) * FW))[e] = make_uint2(h2u(o0), h2u(o1));
          }
        }
      }
    }
    if (ph == 0) __syncthreads();   // switch L2 working set
  }
}

// ---------- fused conv1 lin + scalar head projections ----------
__global__ __launch_bounds__(256) void k_conv1fused(
    const __half* __restrict__ axm, const __half* __restrict__ xh,
    const __half* __restrict__ U1T, const __half* __restrict__ U2T,
    const float* __restrict__ c1, const float* __restrict__ svecs,
    float2* __restrict__ tsd, float2* __restrict__ ssd, int N) {
  __shared__ _Float16 tile[4][16 * HID];
  __shared__ float svec[512];    // [vs|vd|us|ud]
  const int lane = threadIdx.x & 63;
  const int wid = threadIdx.x >> 6;
  const int row0 = blockIdx.x * 64 + wid * 16;
  const int lr = lane & 15;
  const int lk = (lane >> 4) * 8;

  for (int i = threadIdx.x; i < 512; i += 256) svec[i] = svecs[i];

  {
    f16x8 b1[8], b2[8];
    #pragma unroll
    for (int ct = 0; ct < 8; ++ct) {
      const int c = ct * 16 + lr;
      b1[ct] = *(const f16x8*)((const _Float16*)U1T + (size_t)c * IN_X + lk);
      b2[ct] = *(const f16x8*)((const _Float16*)U2T + (size_t)c * IN_X + lk);
    }
    f32x4 acc[8];
    #pragma unroll
    for (int ct = 0; ct < 8; ++ct) {
      float bv = c1[ct * 16 + lr];
      acc[ct] = (f32x4){bv, bv, bv, bv};
    }
    const int rA = min(row0 + lr, N - 1);
    f16x8 a1 = *(const f16x8*)((const _Float16*)axm + (size_t)rA * IN_X + lk);
    f16x8 a2 = *(const f16x8*)((const _Float16*)xh + (size_t)rA * IN_X + lk);
    #pragma unroll
    for (int ct = 0; ct < 8; ++ct)
      acc[ct] = __builtin_amdgcn_mfma_f32_16x16x32_f16(a1, b1[ct], acc[ct], 0, 0, 0);
    #pragma unroll
    for (int ct = 0; ct < 8; ++ct)
      acc[ct] = __builtin_amdgcn_mfma_f32_16x16x32_f16(a2, b2[ct], acc[ct], 0, 0, 0);
    #pragma unroll
    for (int ct = 0; ct < 8; ++ct) {
      #pragma unroll
      for (int r = 0; r < 4; ++r) {
        const int row = (lane >> 4) * 4 + r;
        const int col = ct * 16 + lr;
        int idx = (row * HID + col) ^ ((row & 7) << 3);
        tile[wid][idx] = (_Float16)fmaxf(acc[ct][r], 0.f);
      }
    }
  }
  __syncthreads();

  const int row = lane & 15, q = lane >> 4;
  float ts = 0.f, td = 0.f, ss = 0.f, sd = 0.f;
  #pragma unroll
  for (int t = 0; t < 4; ++t) {
    const int col = q * 32 + t * 8;
    int idx = (row * HID + col) ^ ((row & 7) << 3);
    f16x8 h = *(const f16x8*)&tile[wid][idx];
    #pragma unroll
    for (int i = 0; i < 8; ++i) {
      float hv = (float)h[i];
      ts += hv * svec[col + i];
      td += hv * svec[128 + col + i];
      ss += hv * svec[256 + col + i];
      sd += hv * svec[384 + col + i];
    }
  }
  ts += __shfl_xor(ts, 16, 64); ts += __shfl_xor(ts, 32, 64);
  td += __shfl_xor(td, 16, 64); td += __shfl_xor(td, 32, 64);
  ss += __shfl_xor(ss, 16, 64); ss += __shfl_xor(ss, 32, 64);
  sd += __shfl_xor(sd, 16, 64); sd += __shfl_xor(sd, 32, 64);
  if (q == 0) {
    const int grow = row0 + row;
    if (grow < N) {
      tsd[grow] = make_float2(ts, td);
      ssd[grow] = make_float2(ss, sd);
    }
  }
}

// ---------- conv2 scalar aggregation ----------
__global__ __launch_bounds__(256) void k_scalagg(const float2* __restrict__ tsd,
    const float2* __restrict__ ssd, const int* __restrict__ gns,
    const int* __restrict__ gne, const uint* __restrict__ gorder,
    const float* __restrict__ hb,
    float* __restrict__ gs, float* __restrict__ gd, int N) {
  const int n = blockIdx.x * 256 + threadIdx.x;
  if (n >= N) return;
  const int s = gns[n], t = gne[n];
  float ax = 0.f, ay = 0.f;
  int j = s;
  for (; j + 4 <= t; j += 4) {
    int r0 = (int)gorder[j],     r1 = (int)gorder[j + 1];
    int r2 = (int)gorder[j + 2], r3 = (int)gorder[j + 3];
    float2 a = tsd[r0], b = tsd[r1], c = tsd[r2], d = tsd[r3];
    ax += (a.x + b.x) + (c.x + d.x);
    ay += (a.y + b.y) + (c.y + d.y);
  }
  for (; j < t; ++j) {
    float2 a = tsd[(int)gorder[j]];
    ax += a.x; ay += a.y;
  }
  const float inv = 1.f / fmaxf((float)(t - s), 1.f);
  const float2 sv = ssd[n];
  gs[n] = sv.x + ax * inv + hb[0];
  gd[n] = sv.y + ay * inv + hb[1];
}

// ---------- per-edge: raw = gs[src] + gd[dst] + bp; sigmoid ----------
__global__ __launch_bounds__(256) void k_edge(const float* __restrict__ gs,
    const float* __restrict__ gd, const int* __restrict__ srcI,
    const int* __restrict__ dstI, const float* __restrict__ bp,
    float* __restrict__ out, int E) {
  int e = blockIdx.x * 256 + threadIdx.x;
  if (e >= E) return;
  float raw = gs[srcI[e]] + gd[dstI[e]] + bp[0];
  out[e] = raw;
  out[(size_t)E + e] = 1.f / (1.f + expf(-raw));
}

extern "C" void kernel_launch(void* const* d_in, const int* in_sizes, int n_in,
                              void* d_out, int out_size, void* d_ws, size_t ws_size,
                              hipStream_t stream) {
  const float* x   = (const float*)d_in[0];
  const int*   ei  = (const int*)d_in[1];
  const float* W0  = (const float*)d_in[2];
  const float* b0  = (const float*)d_in[3];
  const float* W1l = (const float*)d_in[4];
  const float* b1l = (const float*)d_in[5];
  const float* W1r = (const float*)d_in[6];
  const float* W2l = (const float*)d_in[7];
  const float* b2l = (const float*)d_in[8];
  const float* W2r = (const float*)d_in[9];
  const float* Wp  = (const float*)d_in[10];
  const float* bp  = (const float*)d_in[11];

  const int N = in_sizes[0] / IN_X;
  const int E = in_sizes[1] / 2;
  const int* srcI = ei;
  const int* dstI = ei + E;
  float* out = (float*)d_out;

  const int NB = (N + BSZ - 1) >> BSHIFT;
  const int nchunk = (E + CHUNK - 1) / CHUNK;

  // workspace layout
  __half* xh  = (__half*)d_ws;                   // [N][32]
  __half* axm = xh + (size_t)N * IN_X;           // [N][32]
  float2* tsd = (float2*)(axm + (size_t)N * IN_X);  // [N]
  float2* ssd = tsd + N;                         // [N]
  float* gs   = (float*)(ssd + N);               // [N]
  float* gd   = gs + N;                          // [N]
  uintptr_t wp = ((uintptr_t)(gd + N) + 15) & ~(uintptr_t)15;
  __half* U1T  = (__half*)wp;                    // [128][32]
  __half* U2T  = U1T + HID * IN_X;
  float* c1    = (float*)(U2T + HID * IN_X);     // [128]
  float* svecs = c1 + HID;                       // [512] = vs|vd|us|ud
  float* hb    = svecs + 512;                    // [2]
  int* gcursor = (int*)(hb + 2);                 // [NBP]
  int* gns     = gcursor + NBP;                  // [N+1]
  int* gne     = gns + N + 1;                    // [N]
  uint* bucketData = (uint*)(gne + N);           // [NBP*CAP]
  uint* gorder     = bucketData + (size_t)NBP * CAP;  // [NBP*CAP]

  const int xblocks = (N * IN_X / 8 + 255) / 256;
  k_prep<<<36 + xblocks, 256, 0, stream>>>(W0, b0, W1l, b1l, W1r, W2l, W2r,
                                           b2l, Wp, U1T, U2T, c1, svecs, hb,
                                           gcursor, x, xh, N * IN_X);
  // fused bucket build
  k_scatfuse<<<nchunk, 512, 0, stream>>>(srcI, dstI, gcursor, bucketData, E);
  // conv1: axm = mean(xh_j) cache-phased + 4-node interleave
  k_baggr32s<<<NB, 512, 0, stream>>>(xh, bucketData, gcursor, axm, gorder,
                                     gns, gne, N, N / 2);
  // fused conv1 lin + scalar head projections
  k_conv1fused<<<(N + 63) / 64, 256, 0, stream>>>(axm, xh, U1T, U2T, c1,
                                                  svecs, tsd, ssd, N);
  // conv2 scalar aggregation
  k_scalagg<<<(N + 255) / 256, 256, 0, stream>>>(tsd, ssd, gns, gne, gorder,
                                                 hb, gs, gd, N);
  // edge head
  k_edge<<<(E + 255) / 256, 256, 0, stream>>>(gs, gd, srcI, dstI, bp, out, E);
}

// Round 21
// 129.368 us; speedup vs baseline: 1.0868x; 1.0847x over previous
//
#include <hip/hip_runtime.h>
#include <hip/hip_bf16.h>
#include <hip/hip_fp16.h>

// GraphSAGE fwd, round 21 — restore R14/R17 best (128.7us measured).
// Plateau evidence: conv1 xh-gather fixed at 43-48us across 8 variants
// (uint2/uint4 widths, pk-f16, cache-phasing, predicated & branchless ILP,
// lin-fusion, BSZ 64/128). Occupancy and FETCH move; time does not ->
// random 64B-segment L2 access rate is the limiter, not a pipe roofline.
// Structure: lin0 folded into conv1 (U1=W0@W1l, U2=W0@W1r, c1 composed);
// conv2 collapsed to per-node scalars (vs=W2l@wps etc) -> 8B L2 gathers;
// one fused bucket-build kernel; cache-phased conv1 gather (BSZ=128);
// light MFMA conv1fused kernel -> tsd/ssd; scalar conv2 agg; edge head.

#define IN_X 32
#define IN_E 64
#define HID 128
#define OUTF 64

#define BSHIFT 7
#define BSZ 128          // nodes per bucket
#define NBP 1024         // padded bucket count
#define CHUNK 4096       // edges per scatter block
#define CAP 4096         // slots per bucket (mean 2560, +30 sigma)

typedef _Float16 f16x8 __attribute__((ext_vector_type(8)));
typedef float f32x4 __attribute__((ext_vector_type(4)));

__device__ __forceinline__ float2 h2f2(uint v) {
  __half2 h = *reinterpret_cast<__half2*>(&v);
  return __half22float2(h);
}
__device__ __forceinline__ __half2 u2h(uint v) {
  return *reinterpret_cast<__half2*>(&v);
}
__device__ __forceinline__ uint h2u(__half2 h) {
  return *reinterpret_cast<uint*>(&h);
}

// ---------- prep: U1T/U2T, c1, head consts, svecs, zero gcursor, xh ----------
__global__ __launch_bounds__(256) void k_prep(
    const float* __restrict__ W0, const float* __restrict__ b0,
    const float* __restrict__ W1l, const float* __restrict__ b1l,
    const float* __restrict__ W1r,
    const float* __restrict__ W2l, const float* __restrict__ W2r,
    const float* __restrict__ b2l, const float* __restrict__ Wp,
    __half* __restrict__ U1T, __half* __restrict__ U2T, float* __restrict__ c1,
    float* __restrict__ svecs, float* __restrict__ hb, int* __restrict__ gcursor,
    const float* __restrict__ x, __half* __restrict__ xh, int xtotal) {
  const int blk = blockIdx.x;
  if (blk < 32) {
    __shared__ float sW0[IN_X * IN_E];
    for (int t = threadIdx.x; t < IN_X * IN_E; t += 256) sW0[t] = W0[t];
    __syncthreads();
    const int o = blk * 256 + threadIdx.x;
    const int hf = o >> 12;
    const int rem = o & 4095;
    const int j = rem >> 5, i = rem & 31;
    const float* W = hf ? W1r : W1l;
    float u = 0.f;
    #pragma unroll 8
    for (int k = 0; k < IN_E; ++k) u += sW0[i * IN_E + k] * W[k * HID + j];
    (hf ? U2T : U1T)[j * IN_X + i] = __float2half(u);
  } else if (blk == 32) {
    const int j = threadIdx.x;
    if (j < HID) {
      float cv = b1l[j];
      for (int k = 0; k < IN_E; ++k)
        cv += b0[k] * (W1l[k * HID + j] + W1r[k * HID + j]);
      c1[j] = cv;
    } else if (j == HID || j == HID + 1) {
      const float* w = Wp + (j - HID) * OUTF;
      float s = 0.f;
      for (int k = 0; k < OUTF; ++k) s += b2l[k] * w[k];
      hb[j - HID] = s;
    }
  } else if (blk == 33 || blk == 34) {
    __shared__ float sW[HID * OUTF];   // 32 KB
    const float* W = (blk == 33) ? W2l : W2r;
    for (int t = threadIdx.x; t < HID * OUTF; t += 256) sW[t] = W[t];
    __syncthreads();
    const int vec = threadIdx.x >> 7;
    const int j = threadIdx.x & 127;
    const float* w = Wp + vec * OUTF;
    float s = 0.f;
    #pragma unroll 8
    for (int k = 0; k < OUTF; ++k) s += sW[j * OUTF + k] * w[k];
    svecs[(blk - 33) * 256 + vec * 128 + j] = s;
  } else if (blk == 35) {
    #pragma unroll
    for (int k = 0; k < NBP / 256; ++k) gcursor[k * 256 + threadIdx.x] = 0;
  } else {
    int i = ((blk - 36) * 256 + threadIdx.x) * 8;
    if (i < xtotal) {
      float4 a = *(const float4*)(x + i);
      float4 b = *(const float4*)(x + i + 4);
      __half2 h0 = __floats2half2_rn(a.x, a.y);
      __half2 h1 = __floats2half2_rn(a.z, a.w);
      __half2 h2 = __floats2half2_rn(b.x, b.y);
      __half2 h3 = __floats2half2_rn(b.z, b.w);
      uint4 o = { *(uint*)&h0, *(uint*)&h1, *(uint*)&h2, *(uint*)&h3 };
      *(uint4*)(xh + i) = o;
    }
  }
}

// ---------- fused bucket build: hist -> global reserve -> scatter ----------
__global__ __launch_bounds__(512) void k_scatfuse(const int* __restrict__ src,
    const int* __restrict__ dst, int* __restrict__ gcursor,
    uint* __restrict__ bucketData, int E) {
  __shared__ int hist[NBP];
  const int cblk = blockIdx.x;
  for (int i = threadIdx.x; i < NBP; i += 512) hist[i] = 0;
  __syncthreads();
  const int base = cblk * CHUNK;
  int d[CHUNK / 512], s[CHUNK / 512];
  #pragma unroll
  for (int k = 0; k < CHUNK / 512; ++k) {
    int e = base + k * 512 + threadIdx.x;
    d[k] = (e < E) ? dst[e] : -1;
    s[k] = (e < E) ? src[e] : 0;
  }
  #pragma unroll
  for (int k = 0; k < CHUNK / 512; ++k)
    if (d[k] >= 0) atomicAdd(&hist[d[k] >> BSHIFT], 1);
  __syncthreads();
  for (int i = threadIdx.x; i < NBP; i += 512) {
    int h = hist[i];
    hist[i] = (h > 0) ? atomicAdd(&gcursor[i], h) : 0;
  }
  __syncthreads();
  #pragma unroll
  for (int k = 0; k < CHUNK / 512; ++k) {
    if (d[k] >= 0) {
      int bkt = d[k] >> BSHIFT;
      int pos = atomicAdd(&hist[bkt], 1);
      if (pos < CAP)
        bucketData[(size_t)bkt * CAP + pos] =
            ((uint)s[k] << BSHIFT) | (uint)(d[k] & (BSZ - 1));
    }
  }
}

// ---------- conv1 aggregation (cache-phased, 4-node interleave) ----------
__global__ __launch_bounds__(512) void k_baggr32s(const __half* __restrict__ feat,
    const uint* __restrict__ bucketData, const int* __restrict__ gcnt,
    __half* __restrict__ aggr, uint* __restrict__ gorder,
    int* __restrict__ gns, int* __restrict__ gne, int N, int Nhalf) {
  constexpr int FW = IN_X;     // 32 halves per row
  __shared__ int nodeStart[2 * BSZ + 1];
  __shared__ int cursor[2 * BSZ];
  __shared__ int order[CAP];
  __shared__ uint2 stash[BSZ * 8];   // 8 KB packed-fp16 partials
  const int b = blockIdx.x;
  const int tid = threadIdx.x;
  const int lane = tid & 63, wid = tid >> 6;
  const int e0 = b * CAP;
  const int cnt = min(gcnt[b], CAP);

  for (int i = tid; i < 2 * BSZ; i += 512) cursor[i] = 0;
  __syncthreads();
  for (int i = tid; i < cnt; i += 512) {
    uint p = bucketData[e0 + i];
    int key = ((p & (BSZ - 1)) << 1) | ((int)(p >> BSHIFT) >= Nhalf ? 1 : 0);
    atomicAdd(&cursor[key], 1);
  }
  __syncthreads();

  // exclusive scan over 256 counters (wave 0, 4 segments of 64 with carry)
  if (wid == 0) {
    int carry = 0;
    #pragma unroll
    for (int seg = 0; seg < 4; ++seg) {
      int v = cursor[seg * 64 + lane];
      int x = v;
      #pragma unroll
      for (int s = 1; s < 64; s <<= 1) {
        int y = __shfl_up(x, s, 64);
        if (lane >= s) x += y;
      }
      nodeStart[seg * 64 + lane] = carry + x - v;
      carry += __shfl(x, 63, 64);
    }
    if (lane == 0) nodeStart[2 * BSZ] = carry;
  }
  __syncthreads();
  for (int i = tid; i < 2 * BSZ; i += 512) cursor[i] = nodeStart[i];
  __syncthreads();

  for (int i = tid; i < cnt; i += 512) {
    uint p = bucketData[e0 + i];
    int key = ((p & (BSZ - 1)) << 1) | ((int)(p >> BSHIFT) >= Nhalf ? 1 : 0);
    int pos = atomicAdd(&cursor[key], 1);
    order[pos] = (int)(p >> BSHIFT);
  }
  __syncthreads();

  // export gapped CSR
  for (int i = tid; i < cnt; i += 512) gorder[e0 + i] = (uint)order[i];
  if (tid < BSZ) {
    const int n = b * BSZ + tid;
    if (n < N) {
      gns[n] = e0 + nodeStart[2 * tid];
      gne[n] = e0 + nodeStart[2 * tid + 2];
    }
  }

  const int nodes = min(BSZ, N - b * BSZ);
  const int g = lane >> 3, e = lane & 7;   // 8 lanes x uint2 = 64B row

  // two phases (ph=0: low-half srcs, ph=1: high-half), 4 nodes interleaved
  #pragma unroll
  for (int ph = 0; ph < 2; ++ph) {
    for (int k = 0; k < 16; k += 4) {
      const int n0 = wid + 8 * k,        n1 = wid + 8 * (k + 1);
      const int n2 = wid + 8 * (k + 2),  n3 = wid + 8 * (k + 3);
      int j0 = (n0 < nodes) ? nodeStart[2 * n0 + ph] : 0;
      int t0 = (n0 < nodes) ? nodeStart[2 * n0 + ph + 1] : 0;
      int j1 = (n1 < nodes) ? nodeStart[2 * n1 + ph] : 0;
      int t1 = (n1 < nodes) ? nodeStart[2 * n1 + ph + 1] : 0;
      int j2 = (n2 < nodes) ? nodeStart[2 * n2 + ph] : 0;
      int t2 = (n2 < nodes) ? nodeStart[2 * n2 + ph + 1] : 0;
      int j3 = (n3 < nodes) ? nodeStart[2 * n3 + ph] : 0;
      int t3 = (n3 < nodes) ? nodeStart[2 * n3 + ph + 1] : 0;
      __half2 ax0 = __floats2half2_rn(0.f, 0.f), ay0 = ax0;
      __half2 ax1 = ax0, ay1 = ax0, ax2 = ax0, ay2 = ax0, ax3 = ax0, ay3 = ax0;
      while (j0 < t0 || j1 < t1 || j2 < t2 || j3 < t3) {
        uint2 v0, v1, v2, v3;
        const bool a0 = j0 + g < t0, a1 = j1 + g < t1;
        const bool a2 = j2 + g < t2, a3 = j3 + g < t3;
        if (a0) { int r = order[j0 + g]; v0 = ((const uint2*)(feat + (size_t)r * FW))[e]; }
        if (a1) { int r = order[j1 + g]; v1 = ((const uint2*)(feat + (size_t)r * FW))[e]; }
        if (a2) { int r = order[j2 + g]; v2 = ((const uint2*)(feat + (size_t)r * FW))[e]; }
        if (a3) { int r = order[j3 + g]; v3 = ((const uint2*)(feat + (size_t)r * FW))[e]; }
        if (a0) { ax0 = __hadd2(ax0, u2h(v0.x)); ay0 = __hadd2(ay0, u2h(v0.y)); }
        if (a1) { ax1 = __hadd2(ax1, u2h(v1.x)); ay1 = __hadd2(ay1, u2h(v1.y)); }
        if (a2) { ax2 = __hadd2(ax2, u2h(v2.x)); ay2 = __hadd2(ay2, u2h(v2.y)); }
        if (a3) { ax3 = __hadd2(ax3, u2h(v3.x)); ay3 = __hadd2(ay3, u2h(v3.y)); }
        j0 += 8; j1 += 8; j2 += 8; j3 += 8;
      }
      // reduce across the 8 row-groups (m = 8,16,32)
      #pragma unroll
      for (int m = 8; m < 64; m <<= 1) {
        ax0 = __hadd2(ax0, u2h((uint)__shfl_xor((int)h2u(ax0), m, 64)));
        ay0 = __hadd2(ay0, u2h((uint)__shfl_xor((int)h2u(ay0), m, 64)));
        ax1 = __hadd2(ax1, u2h((uint)__shfl_xor((int)h2u(ax1), m, 64)));
        ay1 = __hadd2(ay1, u2h((uint)__shfl_xor((int)h2u(ay1), m, 64)));
        ax2 = __hadd2(ax2, u2h((uint)__shfl_xor((int)h2u(ax2), m, 64)));
        ay2 = __hadd2(ay2, u2h((uint)__shfl_xor((int)h2u(ay2), m, 64)));
        ax3 = __hadd2(ax3, u2h((uint)__shfl_xor((int)h2u(ax3), m, 64)));
        ay3 = __hadd2(ay3, u2h((uint)__shfl_xor((int)h2u(ay3), m, 64)));
      }
      if (g == 0) {
        if (ph == 0) {
          if (n0 < nodes) stash[n0 * 8 + e] = make_uint2(h2u(ax0), h2u(ay0));
          if (n1 < nodes) stash[n1 * 8 + e] = make_uint2(h2u(ax1), h2u(ay1));
          if (n2 < nodes) stash[n2 * 8 + e] = make_uint2(h2u(ax2), h2u(ay2));
          if (n3 < nodes) stash[n3 * 8 + e] = make_uint2(h2u(ax3), h2u(ay3));
        } else {
          if (n0 < nodes) {
            uint2 st = stash[n0 * 8 + e];
            ax0 = __hadd2(ax0, u2h(st.x)); ay0 = __hadd2(ay0, u2h(st.y));
            const int deg = nodeStart[2 * n0 + 2] - nodeStart[2 * n0];
            float inv = 1.f / fmaxf((float)deg, 1.f);
            float2 fx = __half22float2(ax0), fy = __half22float2(ay0);
            __half2 o0 = __floats2half2_rn(fx.x * inv, fx.y * inv);
            __half2 o1 = __floats2half2_rn(fy.x * inv, fy.y * inv);
            ((uint2*)(aggr + ((size_t)(b * BSZ + n0)) * FW))[e] = make_uint2(h2u(o0), h2u(o1));
          }
          if (n1 < nodes) {
            uint2 st = stash[n1 * 8 + e];
            ax1 = __hadd2(ax1, u2h(st.x)); ay1 = __hadd2(ay1, u2h(st.y));
            const int deg = nodeStart[2 * n1 + 2] - nodeStart[2 * n1];
            float inv = 1.f / fmaxf((float)deg, 1.f);
            float2 fx = __half22float2(ax1), fy = __half22float2(ay1);
            __half2 o0 = __floats2half2_rn(fx.x * inv, fx.y * inv);
            __half2 o1 = __floats2half2_rn(fy.x * inv, fy.y * inv);
            ((uint2*)(aggr + ((size_t)(b * BSZ + n1)) * FW))[e] = make_uint2(h2u(o0), h2u(o1));
          }
          if (n2 < nodes) {
            uint2 st = stash[n2 * 8 + e];
            ax2 = __hadd2(ax2, u2h(st.x)); ay2 = __hadd2(ay2, u2h(st.y));
            const int deg = nodeStart[2 * n2 + 2] - nodeStart[2 * n2];
            float inv = 1.f / fmaxf((float)deg, 1.f);
            float2 fx = __half22float2(ax2), fy = __half22float2(ay2);
            __half2 o0 = __floats2half2_rn(fx.x * inv, fx.y * inv);
            __half2 o1 = __floats2half2_rn(fy.x * inv, fy.y * inv);
            ((uint2*)(aggr + ((size_t)(b * BSZ + n2)) * FW))[e] = make_uint2(h2u(o0), h2u(o1));
          }
          if (n3 < nodes) {
            uint2 st = stash[n3 * 8 + e];
            ax3 = __hadd2(ax3, u2h(st.x)); ay3 = __hadd2(ay3, u2h(st.y));
            const int deg = nodeStart[2 * n3 + 2] - nodeStart[2 * n3];
            float inv = 1.f / fmaxf((float)deg, 1.f);
            float2 fx = __half22float2(ax3), fy = __half22float2(ay3);
            __half2 o0 = __floats2half2_rn(fx.x * inv, fx.y * inv);
            __half2 o1 = __floats2half2_rn(fy.x * inv, fy.y * inv);
            ((uint2*)(aggr + ((size_t)(b * BSZ + n3)) * FW))[e] = make_uint2(h2u(o0), h2u(o1));
          }
        }
      }
    }
    if (ph == 0) __syncthreads();   // switch L2 working set
  }
}

// ---------- fused conv1 lin + scalar head projections ----------
__global__ __launch_bounds__(256) void k_conv1fused(
    const __half* __restrict__ axm, const __half* __restrict__ xh,
    const __half* __restrict__ U1T, const __half* __restrict__ U2T,
    const float* __restrict__ c1, const float* __restrict__ svecs,
    float2* __restrict__ tsd, float2* __restrict__ ssd, int N) {
  __shared__ _Float16 tile[4][16 * HID];
  __shared__ float svec[512];    // [vs|vd|us|ud]
  const int lane = threadIdx.x & 63;
  const int wid = threadIdx.x >> 6;
  const int row0 = blockIdx.x * 64 + wid * 16;
  const int lr = lane & 15;
  const int lk = (lane >> 4) * 8;

  for (int i = threadIdx.x; i < 512; i += 256) svec[i] = svecs[i];

  {
    f16x8 b1[8], b2[8];
    #pragma unroll
    for (int ct = 0; ct < 8; ++ct) {
      const int c = ct * 16 + lr;
      b1[ct] = *(const f16x8*)((const _Float16*)U1T + (size_t)c * IN_X + lk);
      b2[ct] = *(const f16x8*)((const _Float16*)U2T + (size_t)c * IN_X + lk);
    }
    f32x4 acc[8];
    #pragma unroll
    for (int ct = 0; ct < 8; ++ct) {
      float bv = c1[ct * 16 + lr];
      acc[ct] = (f32x4){bv, bv, bv, bv};
    }
    const int rA = min(row0 + lr, N - 1);
    f16x8 a1 = *(const f16x8*)((const _Float16*)axm + (size_t)rA * IN_X + lk);
    f16x8 a2 = *(const f16x8*)((const _Float16*)xh + (size_t)rA * IN_X + lk);
    #pragma unroll
    for (int ct = 0; ct < 8; ++ct)
      acc[ct] = __builtin_amdgcn_mfma_f32_16x16x32_f16(a1, b1[ct], acc[ct], 0, 0, 0);
    #pragma unroll
    for (int ct = 0; ct < 8; ++ct)
      acc[ct] = __builtin_amdgcn_mfma_f32_16x16x32_f16(a2, b2[ct], acc[ct], 0, 0, 0);
    #pragma unroll
    for (int ct = 0; ct < 8; ++ct) {
      #pragma unroll
      for (int r = 0; r < 4; ++r) {
        const int row = (lane >> 4) * 4 + r;
        const int col = ct * 16 + lr;
        int idx = (row * HID + col) ^ ((row & 7) << 3);
        tile[wid][idx] = (_Float16)fmaxf(acc[ct][r], 0.f);
      }
    }
  }
  __syncthreads();

  const int row = lane & 15, q = lane >> 4;
  float ts = 0.f, td = 0.f, ss = 0.f, sd = 0.f;
  #pragma unroll
  for (int t = 0; t < 4; ++t) {
    const int col = q * 32 + t * 8;
    int idx = (row * HID + col) ^ ((row & 7) << 3);
    f16x8 h = *(const f16x8*)&tile[wid][idx];
    #pragma unroll
    for (int i = 0; i < 8; ++i) {
      float hv = (float)h[i];
      ts += hv * svec[col + i];
      td += hv * svec[128 + col + i];
      ss += hv * svec[256 + col + i];
      sd += hv * svec[384 + col + i];
    }
  }
  ts += __shfl_xor(ts, 16, 64); ts += __shfl_xor(ts, 32, 64);
  td += __shfl_xor(td, 16, 64); td += __shfl_xor(td, 32, 64);
  ss += __shfl_xor(ss, 16, 64); ss += __shfl_xor(ss, 32, 64);
  sd += __shfl_xor(sd, 16, 64); sd += __shfl_xor(sd, 32, 64);
  if (q == 0) {
    const int grow = row0 + row;
    if (grow < N) {
      tsd[grow] = make_float2(ts, td);
      ssd[grow] = make_float2(ss, sd);
    }
  }
}

// ---------- conv2 scalar aggregation ----------
__global__ __launch_bounds__(256) void k_scalagg(const float2* __restrict__ tsd,
    const float2* __restrict__ ssd, const int* __restrict__ gns,
    const int* __restrict__ gne, const uint* __restrict__ gorder,
    const float* __restrict__ hb,
    float* __restrict__ gs, float* __restrict__ gd, int N) {
  const int n = blockIdx.x * 256 + threadIdx.x;
  if (n >= N) return;
  const int s = gns[n], t = gne[n];
  float ax = 0.f, ay = 0.f;
  int j = s;
  for (; j + 4 <= t; j += 4) {
    int r0 = (int)gorder[j],     r1 = (int)gorder[j + 1];
    int r2 = (int)gorder[j + 2], r3 = (int)gorder[j + 3];
    float2 a = tsd[r0], b = tsd[r1], c = tsd[r2], d = tsd[r3];
    ax += (a.x + b.x) + (c.x + d.x);
    ay += (a.y + b.y) + (c.y + d.y);
  }
  for (; j < t; ++j) {
    float2 a = tsd[(int)gorder[j]];
    ax += a.x; ay += a.y;
  }
  const float inv = 1.f / fmaxf((float)(t - s), 1.f);
  const float2 sv = ssd[n];
  gs[n] = sv.x + ax * inv + hb[0];
  gd[n] = sv.y + ay * inv + hb[1];
}

// ---------- per-edge: raw = gs[src] + gd[dst] + bp; sigmoid ----------
__global__ __launch_bounds__(256) void k_edge(const float* __restrict__ gs,
    const float* __restrict__ gd, const int* __restrict__ srcI,
    const int* __restrict__ dstI, const float* __restrict__ bp,
    float* __restrict__ out, int E) {
  int e = blockIdx.x * 256 + threadIdx.x;
  if (e >= E) return;
  float raw = gs[srcI[e]] + gd[dstI[e]] + bp[0];
  out[e] = raw;
  out[(size_t)E + e] = 1.f / (1.f + expf(-raw));
}

extern "C" void kernel_launch(void* const* d_in, const int* in_sizes, int n_in,
                              void* d_out, int out_size, void* d_ws, size_t ws_size,
                              hipStream_t stream) {
  const float* x   = (const float*)d_in[0];
  const int*   ei  = (const int*)d_in[1];
  const float* W0  = (const float*)d_in[2];
  const float* b0  = (const float*)d_in[3];
  const float* W1l = (const float*)d_in[4];
  const float* b1l = (const float*)d_in[5];
  const float* W1r = (const float*)d_in[6];
  const float* W2l = (const float*)d_in[7];
  const float* b2l = (const float*)d_in[8];
  const float* W2r = (const float*)d_in[9];
  const float* Wp  = (const float*)d_in[10];
  const float* bp  = (const float*)d_in[11];

  const int N = in_sizes[0] / IN_X;
  const int E = in_sizes[1] / 2;
  const int* srcI = ei;
  const int* dstI = ei + E;
  float* out = (float*)d_out;

  const int NB = (N + BSZ - 1) >> BSHIFT;
  const int nchunk = (E + CHUNK - 1) / CHUNK;

  // workspace layout
  __half* xh  = (__half*)d_ws;                   // [N][32]
  __half* axm = xh + (size_t)N * IN_X;           // [N][32]
  float2* tsd = (float2*)(axm + (size_t)N * IN_X);  // [N]
  float2* ssd = tsd + N;                         // [N]
  float* gs   = (float*)(ssd + N);               // [N]
  float* gd   = gs + N;                          // [N]
  uintptr_t wp = ((uintptr_t)(gd + N) + 15) & ~(uintptr_t)15;
  __half* U1T  = (__half*)wp;                    // [128][32]
  __half* U2T  = U1T + HID * IN_X;
  float* c1    = (float*)(U2T + HID * IN_X);     // [128]
  float* svecs = c1 + HID;                       // [512] = vs|vd|us|ud
  float* hb    = svecs + 512;                    // [2]
  int* gcursor = (int*)(hb + 2);                 // [NBP]
  int* gns     = gcursor + NBP;                  // [N+1]
  int* gne     = gns + N + 1;                    // [N]
  uint* bucketData = (uint*)(gne + N);           // [NBP*CAP]
  uint* gorder     = bucketData + (size_t)NBP * CAP;  // [NBP*CAP]

  const int xblocks = (N * IN_X / 8 + 255) / 256;
  k_prep<<<36 + xblocks, 256, 0, stream>>>(W0, b0, W1l, b1l, W1r, W2l, W2r,
                                           b2l, Wp, U1T, U2T, c1, svecs, hb,
                                           gcursor, x, xh, N * IN_X);
  // fused bucket build
  k_scatfuse<<<nchunk, 512, 0, stream>>>(srcI, dstI, gcursor, bucketData, E);
  // conv1: axm = mean(xh_j) cache-phased + 4-node interleave
  k_baggr32s<<<NB, 512, 0, stream>>>(xh, bucketData, gcursor, axm, gorder,
                                     gns, gne, N, N / 2);
  // fused conv1 lin + scalar head projections
  k_conv1fused<<<(N + 63) / 64, 256, 0, stream>>>(axm, xh, U1T, U2T, c1,
                                                  svecs, tsd, ssd, N);
  // conv2 scalar aggregation
  k_scalagg<<<(N + 255) / 256, 256, 0, stream>>>(tsd, ssd, gns, gne, gorder,
                                                 hb, gs, gd, N);
  // edge head
  k_edge<<<(E + 255) / 256, 256, 0, stream>>>(gs, gd, srcI, dstI, bp, out, E);
}

// Round 22
// 128.711 us; speedup vs baseline: 1.0923x; 1.0051x over previous
//
#include <hip/hip_runtime.h>
#include <hip/hip_bf16.h>
#include <hip/hip_fp16.h>

// GraphSAGE fwd, round 21 — restore R14/R17 best (128.7us measured).
// Plateau evidence: conv1 xh-gather fixed at 43-48us across 8 variants
// (uint2/uint4 widths, pk-f16, cache-phasing, predicated & branchless ILP,
// lin-fusion, BSZ 64/128). Occupancy and FETCH move; time does not ->
// random 64B-segment L2 access rate is the limiter, not a pipe roofline.
// Structure: lin0 folded into conv1 (U1=W0@W1l, U2=W0@W1r, c1 composed);
// conv2 collapsed to per-node scalars (vs=W2l@wps etc) -> 8B L2 gathers;
// one fused bucket-build kernel; cache-phased conv1 gather (BSZ=128);
// light MFMA conv1fused kernel -> tsd/ssd; scalar conv2 agg; edge head.

#define IN_X 32
#define IN_E 64
#define HID 128
#define OUTF 64

#define BSHIFT 7
#define BSZ 128          // nodes per bucket
#define NBP 1024         // padded bucket count
#define CHUNK 4096       // edges per scatter block
#define CAP 4096         // slots per bucket (mean 2560, +30 sigma)

typedef _Float16 f16x8 __attribute__((ext_vector_type(8)));
typedef float f32x4 __attribute__((ext_vector_type(4)));

__device__ __forceinline__ float2 h2f2(uint v) {
  __half2 h = *reinterpret_cast<__half2*>(&v);
  return __half22float2(h);
}
__device__ __forceinline__ __half2 u2h(uint v) {
  return *reinterpret_cast<__half2*>(&v);
}
__device__ __forceinline__ uint h2u(__half2 h) {
  return *reinterpret_cast<uint*>(&h);
}

// ---------- prep: U1T/U2T, c1, head consts, svecs, zero gcursor, xh ----------
__global__ __launch_bounds__(256) void k_prep(
    const float* __restrict__ W0, const float* __restrict__ b0,
    const float* __restrict__ W1l, const float* __restrict__ b1l,
    const float* __restrict__ W1r,
    const float* __restrict__ W2l, const float* __restrict__ W2r,
    const float* __restrict__ b2l, const float* __restrict__ Wp,
    __half* __restrict__ U1T, __half* __restrict__ U2T, float* __restrict__ c1,
    float* __restrict__ svecs, float* __restrict__ hb, int* __restrict__ gcursor,
    const float* __restrict__ x, __half* __restrict__ xh, int xtotal) {
  const int blk = blockIdx.x;
  if (blk < 32) {
    __shared__ float sW0[IN_X * IN_E];
    for (int t = threadIdx.x; t < IN_X * IN_E; t += 256) sW0[t] = W0[t];
    __syncthreads();
    const int o = blk * 256 + threadIdx.x;
    const int hf = o >> 12;
    const int rem = o & 4095;
    const int j = rem >> 5, i = rem & 31;
    const float* W = hf ? W1r : W1l;
    float u = 0.f;
    #pragma unroll 8
    for (int k = 0; k < IN_E; ++k) u += sW0[i * IN_E + k] * W[k * HID + j];
    (hf ? U2T : U1T)[j * IN_X + i] = __float2half(u);
  } else if (blk == 32) {
    const int j = threadIdx.x;
    if (j < HID) {
      float cv = b1l[j];
      for (int k = 0; k < IN_E; ++k)
        cv += b0[k] * (W1l[k * HID + j] + W1r[k * HID + j]);
      c1[j] = cv;
    } else if (j == HID || j == HID + 1) {
      const float* w = Wp + (j - HID) * OUTF;
      float s = 0.f;
      for (int k = 0; k < OUTF; ++k) s += b2l[k] * w[k];
      hb[j - HID] = s;
    }
  } else if (blk == 33 || blk == 34) {
    __shared__ float sW[HID * OUTF];   // 32 KB
    const float* W = (blk == 33) ? W2l : W2r;
    for (int t = threadIdx.x; t < HID * OUTF; t += 256) sW[t] = W[t];
    __syncthreads();
    const int vec = threadIdx.x >> 7;
    const int j = threadIdx.x & 127;
    const float* w = Wp + vec * OUTF;
    float s = 0.f;
    #pragma unroll 8
    for (int k = 0; k < OUTF; ++k) s += sW[j * OUTF + k] * w[k];
    svecs[(blk - 33) * 256 + vec * 128 + j] = s;
  } else if (blk == 35) {
    #pragma unroll
    for (int k = 0; k < NBP / 256; ++k) gcursor[k * 256 + threadIdx.x] = 0;
  } else {
    int i = ((blk - 36) * 256 + threadIdx.x) * 8;
    if (i < xtotal) {
      float4 a = *(const float4*)(x + i);
      float4 b = *(const float4*)(x + i + 4);
      __half2 h0 = __floats2half2_rn(a.x, a.y);
      __half2 h1 = __floats2half2_rn(a.z, a.w);
      __half2 h2 = __floats2half2_rn(b.x, b.y);
      __half2 h3 = __floats2half2_rn(b.z, b.w);
      uint4 o = { *(uint*)&h0, *(uint*)&h1, *(uint*)&h2, *(uint*)&h3 };
      *(uint4*)(xh + i) = o;
    }
  }
}

// ---------- fused bucket build: hist -> global reserve -> scatter ----------
__global__ __launch_bounds__(512) void k_scatfuse(const int* __restrict__ src,
    const int* __restrict__ dst, int* __restrict__ gcursor,
    uint* __restrict__ bucketData, int E) {
  __shared__ int hist[NBP];
  const int cblk = blockIdx.x;
  for (int i = threadIdx.x; i < NBP; i += 512) hist[i] = 0;
  __syncthreads();
  const int base = cblk * CHUNK;
  int d[CHUNK / 512], s[CHUNK / 512];
  #pragma unroll
  for (int k = 0; k < CHUNK / 512; ++k) {
    int e = base + k * 512 + threadIdx.x;
    d[k] = (e < E) ? dst[e] : -1;
    s[k] = (e < E) ? src[e] : 0;
  }
  #pragma unroll
  for (int k = 0; k < CHUNK / 512; ++k)
    if (d[k] >= 0) atomicAdd(&hist[d[k] >> BSHIFT], 1);
  __syncthreads();
  for (int i = threadIdx.x; i < NBP; i += 512) {
    int h = hist[i];
    hist[i] = (h > 0) ? atomicAdd(&gcursor[i], h) : 0;
  }
  __syncthreads();
  #pragma unroll
  for (int k = 0; k < CHUNK / 512; ++k) {
    if (d[k] >= 0) {
      int bkt = d[k] >> BSHIFT;
      int pos = atomicAdd(&hist[bkt], 1);
      if (pos < CAP)
        bucketData[(size_t)bkt * CAP + pos] =
            ((uint)s[k] << BSHIFT) | (uint)(d[k] & (BSZ - 1));
    }
  }
}

// ---------- conv1 aggregation (cache-phased, 4-node interleave) ----------
__global__ __launch_bounds__(512) void k_baggr32s(const __half* __restrict__ feat,
    const uint* __restrict__ bucketData, const int* __restrict__ gcnt,
    __half* __restrict__ aggr, uint* __restrict__ gorder,
    int* __restrict__ gns, int* __restrict__ gne, int N, int Nhalf) {
  constexpr int FW = IN_X;     // 32 halves per row
  __shared__ int nodeStart[2 * BSZ + 1];
  __shared__ int cursor[2 * BSZ];
  __shared__ int order[CAP];
  __shared__ uint2 stash[BSZ * 8];   // 8 KB packed-fp16 partials
  const int b = blockIdx.x;
  const int tid = threadIdx.x;
  const int lane = tid & 63, wid = tid >> 6;
  const int e0 = b * CAP;
  const int cnt = min(gcnt[b], CAP);

  for (int i = tid; i < 2 * BSZ; i += 512) cursor[i] = 0;
  __syncthreads();
  for (int i = tid; i < cnt; i += 512) {
    uint p = bucketData[e0 + i];
    int key = ((p & (BSZ - 1)) << 1) | ((int)(p >> BSHIFT) >= Nhalf ? 1 : 0);
    atomicAdd(&cursor[key], 1);
  }
  __syncthreads();

  // exclusive scan over 256 counters (wave 0, 4 segments of 64 with carry)
  if (wid == 0) {
    int carry = 0;
    #pragma unroll
    for (int seg = 0; seg < 4; ++seg) {
      int v = cursor[seg * 64 + lane];
      int x = v;
      #pragma unroll
      for (int s = 1; s < 64; s <<= 1) {
        int y = __shfl_up(x, s, 64);
        if (lane >= s) x += y;
      }
      nodeStart[seg * 64 + lane] = carry + x - v;
      carry += __shfl(x, 63, 64);
    }
    if (lane == 0) nodeStart[2 * BSZ] = carry;
  }
  __syncthreads();
  for (int i = tid; i < 2 * BSZ; i += 512) cursor[i] = nodeStart[i];
  __syncthreads();

  for (int i = tid; i < cnt; i += 512) {
    uint p = bucketData[e0 + i];
    int key = ((p & (BSZ - 1)) << 1) | ((int)(p >> BSHIFT) >= Nhalf ? 1 : 0);
    int pos = atomicAdd(&cursor[key], 1);
    order[pos] = (int)(p >> BSHIFT);
  }
  __syncthreads();

  // export gapped CSR
  for (int i = tid; i < cnt; i += 512) gorder[e0 + i] = (uint)order[i];
  if (tid < BSZ) {
    const int n = b * BSZ + tid;
    if (n < N) {
      gns[n] = e0 + nodeStart[2 * tid];
      gne[n] = e0 + nodeStart[2 * tid + 2];
    }
  }

  const int nodes = min(BSZ, N - b * BSZ);
  const int g = lane >> 3, e = lane & 7;   // 8 lanes x uint2 = 64B row

  // two phases (ph=0: low-half srcs, ph=1: high-half), 4 nodes interleaved
  #pragma unroll
  for (int ph = 0; ph < 2; ++ph) {
    for (int k = 0; k < 16; k += 4) {
      const int n0 = wid + 8 * k,        n1 = wid + 8 * (k + 1);
      const int n2 = wid + 8 * (k + 2),  n3 = wid + 8 * (k + 3);
      int j0 = (n0 < nodes) ? nodeStart[2 * n0 + ph] : 0;
      int t0 = (n0 < nodes) ? nodeStart[2 * n0 + ph + 1] : 0;
      int j1 = (n1 < nodes) ? nodeStart[2 * n1 + ph] : 0;
      int t1 = (n1 < nodes) ? nodeStart[2 * n1 + ph + 1] : 0;
      int j2 = (n2 < nodes) ? nodeStart[2 * n2 + ph] : 0;
      int t2 = (n2 < nodes) ? nodeStart[2 * n2 + ph + 1] : 0;
      int j3 = (n3 < nodes) ? nodeStart[2 * n3 + ph] : 0;
      int t3 = (n3 < nodes) ? nodeStart[2 * n3 + ph + 1] : 0;
      __half2 ax0 = __floats2half2_rn(0.f, 0.f), ay0 = ax0;
      __half2 ax1 = ax0, ay1 = ax0, ax2 = ax0, ay2 = ax0, ax3 = ax0, ay3 = ax0;
      while (j0 < t0 || j1 < t1 || j2 < t2 || j3 < t3) {
        uint2 v0, v1, v2, v3;
        const bool a0 = j0 + g < t0, a1 = j1 + g < t1;
        const bool a2 = j2 + g < t2, a3 = j3 + g < t3;
        if (a0) { int r = order[j0 + g]; v0 = ((const uint2*)(feat + (size_t)r * FW))[e]; }
        if (a1) { int r = order[j1 + g]; v1 = ((const uint2*)(feat + (size_t)r * FW))[e]; }
        if (a2) { int r = order[j2 + g]; v2 = ((const uint2*)(feat + (size_t)r * FW))[e]; }
        if (a3) { int r = order[j3 + g]; v3 = ((const uint2*)(feat + (size_t)r * FW))[e]; }
        if (a0) { ax0 = __hadd2(ax0, u2h(v0.x)); ay0 = __hadd2(ay0, u2h(v0.y)); }
        if (a1) { ax1 = __hadd2(ax1, u2h(v1.x)); ay1 = __hadd2(ay1, u2h(v1.y)); }
        if (a2) { ax2 = __hadd2(ax2, u2h(v2.x)); ay2 = __hadd2(ay2, u2h(v2.y)); }
        if (a3) { ax3 = __hadd2(ax3, u2h(v3.x)); ay3 = __hadd2(ay3, u2h(v3.y)); }
        j0 += 8; j1 += 8; j2 += 8; j3 += 8;
      }
      // reduce across the 8 row-groups (m = 8,16,32)
      #pragma unroll
      for (int m = 8; m < 64; m <<= 1) {
        ax0 = __hadd2(ax0, u2h((uint)__shfl_xor((int)h2u(ax0), m, 64)));
        ay0 = __hadd2(ay0, u2h((uint)__shfl_xor((int)h2u(ay0), m, 64)));
        ax1 = __hadd2(ax1, u2h((uint)__shfl_xor((int)h2u(ax1), m, 64)));
        ay1 = __hadd2(ay1, u2h((uint)__shfl_xor((int)h2u(ay1), m, 64)));
        ax2 = __hadd2(ax2, u2h((uint)__shfl_xor((int)h2u(ax2), m, 64)));
        ay2 = __hadd2(ay2, u2h((uint)__shfl_xor((int)h2u(ay2), m, 64)));
        ax3 = __hadd2(ax3, u2h((uint)__shfl_xor((int)h2u(ax3), m, 64)));
        ay3 = __hadd2(ay3, u2h((uint)__shfl_xor((int)h2u(ay3), m, 64)));
      }
      if (g == 0) {
        if (ph == 0) {
          if (n0 < nodes) stash[n0 * 8 + e] = make_uint2(h2u(ax0), h2u(ay0));
          if (n1 < nodes) stash[n1 * 8 + e] = make_uint2(h2u(ax1), h2u(ay1));
          if (n2 < nodes) stash[n2 * 8 + e] = make_uint2(h2u(ax2), h2u(ay2));
          if (n3 < nodes) stash[n3 * 8 + e] = make_uint2(h2u(ax3), h2u(ay3));
        } else {
          if (n0 < nodes) {
            uint2 st = stash[n0 * 8 + e];
            ax0 = __hadd2(ax0, u2h(st.x)); ay0 = __hadd2(ay0, u2h(st.y));
            const int deg = nodeStart[2 * n0 + 2] - nodeStart[2 * n0];
            float inv = 1.f / fmaxf((float)deg, 1.f);
            float2 fx = __half22float2(ax0), fy = __half22float2(ay0);
            __half2 o0 = __floats2half2_rn(fx.x * inv, fx.y * inv);
            __half2 o1 = __floats2half2_rn(fy.x * inv, fy.y * inv);
            ((uint2*)(aggr + ((size_t)(b * BSZ + n0)) * FW))[e] = make_uint2(h2u(o0), h2u(o1));
          }
          if (n1 < nodes) {
            uint2 st = stash[n1 * 8 + e];
            ax1 = __hadd2(ax1, u2h(st.x)); ay1 = __hadd2(ay1, u2h(st.y));
            const int deg = nodeStart[2 * n1 + 2] - nodeStart[2 * n1];
            float inv = 1.f / fmaxf((float)deg, 1.f);
            float2 fx = __half22float2(ax1), fy = __half22float2(ay1);
            __half2 o0 = __floats2half2_rn(fx.x * inv, fx.y * inv);
            __half2 o1 = __floats2half2_rn(fy.x * inv, fy.y * inv);
            ((uint2*)(aggr + ((size_t)(b * BSZ + n1)) * FW))[e] = make_uint2(h2u(o0), h2u(o1));
          }
          if (n2 < nodes) {
            uint2 st = stash[n2 * 8 + e];
            ax2 = __hadd2(ax2, u2h(st.x)); ay2 = __hadd2(ay2, u2h(st.y));
            const int deg = nodeStart[2 * n2 + 2] - nodeStart[2 * n2];
            float inv = 1.f / fmaxf((float)deg, 1.f);
            float2 fx = __half22float2(ax2), fy = __half22float2(ay2);
            __half2 o0 = __floats2half2_rn(fx.x * inv, fx.y * inv);
            __half2 o1 = __floats2half2_rn(fy.x * inv, fy.y * inv);
            ((uint2*)(aggr + ((size_t)(b * BSZ + n2)) * FW))[e] = make_uint2(h2u(o0), h2u(o1));
          }
          if (n3 < nodes) {
            uint2 st = stash[n3 * 8 + e];
            ax3 = __hadd2(ax3, u2h(st.x)); ay3 = __hadd2(ay3, u2h(st.y));
            const int deg = nodeStart[2 * n3 + 2] - nodeStart[2 * n3];
            float inv = 1.f / fmaxf((float)deg, 1.f);
            float2 fx = __half22float2(ax3), fy = __half22float2(ay3);
            __half2 o0 = __floats2half2_rn(fx.x * inv, fx.y * inv);
            __half2 o1 = __floats2half2_rn(fy.x * inv, fy.y * inv);
            ((uint2*)(aggr + ((size_t)(b * BSZ + n3)) * FW))[e] = make_uint2(h2u(o0), h2u(o1));
          }
        }
      }
    }
    if (ph == 0) __syncthreads();   // switch L2 working set
  }
}

// ---------- fused conv1 lin + scalar head projections ----------
__global__ __launch_bounds__(256) void k_conv1fused(
    const __half* __restrict__ axm, const __half* __restrict__ xh,
    const __half* __restrict__ U1T, const __half* __restrict__ U2T,
    const float* __restrict__ c1, const float* __restrict__ svecs,
    float2* __restrict__ tsd, float2* __restrict__ ssd, int N) {
  __shared__ _Float16 tile[4][16 * HID];
  __shared__ float svec[512];    // [vs|vd|us|ud]
  const int lane = threadIdx.x & 63;
  const int wid = threadIdx.x >> 6;
  const int row0 = blockIdx.x * 64 + wid * 16;
  const int lr = lane & 15;
  const int lk = (lane >> 4) * 8;

  for (int i = threadIdx.x; i < 512; i += 256) svec[i] = svecs[i];

  {
    f16x8 b1[8], b2[8];
    #pragma unroll
    for (int ct = 0; ct < 8; ++ct) {
      const int c = ct * 16 + lr;
      b1[ct] = *(const f16x8*)((const _Float16*)U1T + (size_t)c * IN_X + lk);
      b2[ct] = *(const f16x8*)((const _Float16*)U2T + (size_t)c * IN_X + lk);
    }
    f32x4 acc[8];
    #pragma unroll
    for (int ct = 0; ct < 8; ++ct) {
      float bv = c1[ct * 16 + lr];
      acc[ct] = (f32x4){bv, bv, bv, bv};
    }
    const int rA = min(row0 + lr, N - 1);
    f16x8 a1 = *(const f16x8*)((const _Float16*)axm + (size_t)rA * IN_X + lk);
    f16x8 a2 = *(const f16x8*)((const _Float16*)xh + (size_t)rA * IN_X + lk);
    #pragma unroll
    for (int ct = 0; ct < 8; ++ct)
      acc[ct] = __builtin_amdgcn_mfma_f32_16x16x32_f16(a1, b1[ct], acc[ct], 0, 0, 0);
    #pragma unroll
    for (int ct = 0; ct < 8; ++ct)
      acc[ct] = __builtin_amdgcn_mfma_f32_16x16x32_f16(a2, b2[ct], acc[ct], 0, 0, 0);
    #pragma unroll
    for (int ct = 0; ct < 8; ++ct) {
      #pragma unroll
      for (int r = 0; r < 4; ++r) {
        const int row = (lane >> 4) * 4 + r;
        const int col = ct * 16 + lr;
        int idx = (row * HID + col) ^ ((row & 7) << 3);
        tile[wid][idx] = (_Float16)fmaxf(acc[ct][r], 0.f);
      }
    }
  }
  __syncthreads();

  const int row = lane & 15, q = lane >> 4;
  float ts = 0.f, td = 0.f, ss = 0.f, sd = 0.f;
  #pragma unroll
  for (int t = 0; t < 4; ++t) {
    const int col = q * 32 + t * 8;
    int idx = (row * HID + col) ^ ((row & 7) << 3);
    f16x8 h = *(const f16x8*)&tile[wid][idx];
    #pragma unroll
    for (int i = 0; i < 8; ++i) {
      float hv = (float)h[i];
      ts += hv * svec[col + i];
      td += hv * svec[128 + col + i];
      ss += hv * svec[256 + col + i];
      sd += hv * svec[384 + col + i];
    }
  }
  ts += __shfl_xor(ts, 16, 64); ts += __shfl_xor(ts, 32, 64);
  td += __shfl_xor(td, 16, 64); td += __shfl_xor(td, 32, 64);
  ss += __shfl_xor(ss, 16, 64); ss += __shfl_xor(ss, 32, 64);
  sd += __shfl_xor(sd, 16, 64); sd += __shfl_xor(sd, 32, 64);
  if (q == 0) {
    const int grow = row0 + row;
    if (grow < N) {
      tsd[grow] = make_float2(ts, td);
      ssd[grow] = make_float2(ss, sd);
    }
  }
}

// ---------- conv2 scalar aggregation ----------
__global__ __launch_bounds__(256) void k_scalagg(const float2* __restrict__ tsd,
    const float2* __restrict__ ssd, const int* __restrict__ gns,
    const int* __restrict__ gne, const uint* __restrict__ gorder,
    const float* __restrict__ hb,
    float* __restrict__ gs, float* __restrict__ gd, int N) {
  const int n = blockIdx.x * 256 + threadIdx.x;
  if (n >= N) return;
  const int s = gns[n], t = gne[n];
  float ax = 0.f, ay = 0.f;
  int j = s;
  for (; j + 4 <= t; j += 4) {
    int r0 = (int)gorder[j],     r1 = (int)gorder[j + 1];
    int r2 = (int)gorder[j + 2], r3 = (int)gorder[j + 3];
    float2 a = tsd[r0], b = tsd[r1], c = tsd[r2], d = tsd[r3];
    ax += (a.x + b.x) + (c.x + d.x);
    ay += (a.y + b.y) + (c.y + d.y);
  }
  for (; j < t; ++j) {
    float2 a = tsd[(int)gorder[j]];
    ax += a.x; ay += a.y;
  }
  const float inv = 1.f / fmaxf((float)(t - s), 1.f);
  const float2 sv = ssd[n];
  gs[n] = sv.x + ax * inv + hb[0];
  gd[n] = sv.y + ay * inv + hb[1];
}

// ---------- per-edge: raw = gs[src] + gd[dst] + bp; sigmoid ----------
__global__ __launch_bounds__(256) void k_edge(const float* __restrict__ gs,
    const float* __restrict__ gd, const int* __restrict__ srcI,
    const int* __restrict__ dstI, const float* __restrict__ bp,
    float* __restrict__ out, int E) {
  int e = blockIdx.x * 256 + threadIdx.x;
  if (e >= E) return;
  float raw = gs[srcI[e]] + gd[dstI[e]] + bp[0];
  out[e] = raw;
  out[(size_t)E + e] = 1.f / (1.f + expf(-raw));
}

extern "C" void kernel_launch(void* const* d_in, const int* in_sizes, int n_in,
                              void* d_out, int out_size, void* d_ws, size_t ws_size,
                              hipStream_t stream) {
  const float* x   = (const float*)d_in[0];
  const int*   ei  = (const int*)d_in[1];
  const float* W0  = (const float*)d_in[2];
  const float* b0  = (const float*)d_in[3];
  const float* W1l = (const float*)d_in[4];
  const float* b1l = (const float*)d_in[5];
  const float* W1r = (const float*)d_in[6];
  const float* W2l = (const float*)d_in[7];
  const float* b2l = (const float*)d_in[8];
  const float* W2r = (const float*)d_in[9];
  const float* Wp  = (const float*)d_in[10];
  const float* bp  = (const float*)d_in[11];

  const int N = in_sizes[0] / IN_X;
  const int E = in_sizes[1] / 2;
  const int* srcI = ei;
  const int* dstI = ei + E;
  float* out = (float*)d_out;

  const int NB = (N + BSZ - 1) >> BSHIFT;
  const int nchunk = (E + CHUNK - 1) / CHUNK;

  // workspace layout
  __half* xh  = (__half*)d_ws;                   // [N][32]
  __half* axm = xh + (size_t)N * IN_X;           // [N][32]
  float2* tsd = (float2*)(axm + (size_t)N * IN_X);  // [N]
  float2* ssd = tsd + N;                         // [N]
  float* gs   = (float*)(ssd + N);               // [N]
  float* gd   = gs + N;                          // [N]
  uintptr_t wp = ((uintptr_t)(gd + N) + 15) & ~(uintptr_t)15;
  __half* U1T  = (__half*)wp;                    // [128][32]
  __half* U2T  = U1T + HID * IN_X;
  float* c1    = (float*)(U2T + HID * IN_X);     // [128]
  float* svecs = c1 + HID;                       // [512] = vs|vd|us|ud
  float* hb    = svecs + 512;                    // [2]
  int* gcursor = (int*)(hb + 2);                 // [NBP]
  int* gns     = gcursor + NBP;                  // [N+1]
  int* gne     = gns + N + 1;                    // [N]
  uint* bucketData = (uint*)(gne + N);           // [NBP*CAP]
  uint* gorder     = bucketData + (size_t)NBP * CAP;  // [NBP*CAP]

  const int xblocks = (N * IN_X / 8 + 255) / 256;
  k_prep<<<36 + xblocks, 256, 0, stream>>>(W0, b0, W1l, b1l, W1r, W2l, W2r,
                                           b2l, Wp, U1T, U2T, c1, svecs, hb,
                                           gcursor, x, xh, N * IN_X);
  // fused bucket build
  k_scatfuse<<<nchunk, 512, 0, stream>>>(srcI, dstI, gcursor, bucketData, E);
  // conv1: axm = mean(xh_j) cache-phased + 4-node interleave
  k_baggr32s<<<NB, 512, 0, stream>>>(xh, bucketData, gcursor, axm, gorder,
                                     gns, gne, N, N / 2);
  // fused conv1 lin + scalar head projections
  k_conv1fused<<<(N + 63) / 64, 256, 0, stream>>>(axm, xh, U1T, U2T, c1,
                                                  svecs, tsd, ssd, N);
  // conv2 scalar aggregation
  k_scalagg<<<(N + 255) / 256, 256, 0, stream>>>(tsd, ssd, gns, gne, gorder,
                                                 hb, gs, gd, N);
  // edge head
  k_edge<<<(E + 255) / 256, 256, 0, stream>>>(gs, gd, srcI, dstI, bp, out, E);
}